// Round 1
// baseline (1309.767 us; speedup 1.0000x reference)
//
#include <hip/hip_runtime.h>
#include <math.h>

#define OUTC 304

// ---------------- init: out[:,0:16] = ecfp, out[:,16:304] = 0 ----------------
__global__ __launch_bounds__(256) void k_init(const float* __restrict__ ecfp,
                                              float* __restrict__ out,
                                              int total4) {
    int i = blockIdx.x * 256 + threadIdx.x;   // float4 index over (N, 76)
    if (i >= total4) return;
    int row = i / 76;
    int c4  = i - row * 76;
    float4 v = make_float4(0.f, 0.f, 0.f, 0.f);
    if (c4 < 4) v = ((const float4*)ecfp)[row * 4 + c4];
    ((float4*)out)[i] = v;
}

// ---------------- radial AEV scatter ----------------
__global__ __launch_bounds__(256) void k_radial(const float* __restrict__ dist,
                                                const float* __restrict__ sw,
                                                const int*   __restrict__ bond_order,
                                                const int*   __restrict__ esrc,
                                                const int*   __restrict__ edst,
                                                const int*   __restrict__ species,
                                                float* __restrict__ out,
                                                int e_rad) {
    int e = blockIdx.x * 256 + threadIdx.x;
    if (e >= e_rad) return;
    float d = dist[e];
    float s = sw[e];
    int   bo = bond_order[e];
    // weights_bo = [1.0,1.5,2.0,0.5,3.0,0.25]; slot 1 iff weight < 1 (bo==3 || bo==5)
    int bb = (bo == 3 || bo == 5) ? 1 : 0;
    int z  = species[edst[e]];
    int sp = (z == 6) ? 1 : (z == 7) ? 2 : (z == 8) ? 3 : 0;
    int src = esrc[e];
    float* base = out + (size_t)src * OUTC + 16 + sp * 32 + bb;
    float coef = 0.25f * s;
#pragma unroll
    for (int r = 0; r < 16; ++r) {
        float delta = d - (0.8f + 0.275f * (float)r);
        float v = coef * __expf(-16.0f * delta * delta);
        if (v > 6e-7f) unsafeAtomicAdd(base + r * 2, v);
    }
}

// ---------------- angular AEV scatter ----------------
__global__ __launch_bounds__(256) void k_ang(const float* __restrict__ angles,
                                             const float* __restrict__ angd,
                                             const float* __restrict__ angsw,
                                             const int*   __restrict__ aedst,
                                             const int*   __restrict__ species,
                                             const int*   __restrict__ central,
                                             const int*   __restrict__ psrc,
                                             const int*   __restrict__ pdst,
                                             float* __restrict__ out,
                                             int n_pairs) {
    int p = blockIdx.x * 256 + threadIdx.x;
    if (p >= n_pairs) return;
    int is = psrc[p];
    int it = pdst[p];
    float th = angles[p];
    float ds = angd[is], dt = angd[it];
    float ss = angsw[is], st = angsw[it];
    int zs = species[aedst[is]];
    int zt = species[aedst[it]];
    int sps = (zs == 6) ? 1 : (zs == 7) ? 2 : (zs == 8) ? 3 : 0;
    int spt = (zt == 6) ? 1 : (zt == 7) ? 2 : (zt == 8) ? 3 : 0;
    int i = min(sps, spt), j = max(sps, spt);
    // triu pair index: offset(i) = i*4 - i*(i-1)/2, + (j-i)
    int pair = i * 4 - (i * (i - 1)) / 2 + (j - i);

    float d12   = 0.5f * (ds + dt);
    float scale = 2.0f * ss * st;

    float sth, cth;
    __sincosf(th, &sth, &cth);
    // shiftZ = pi/8 + z*pi/4 ; cos(th - sz) = cth*cos(sz) + sth*sin(sz)
    const float CZ0 =  0.92387953251f, SZ0 = 0.38268343236f; // pi/8
    const float CZ1 =  0.38268343236f, SZ1 = 0.92387953251f; // 3pi/8
    const float CZ2 = -0.38268343236f, SZ2 = 0.92387953251f; // 5pi/8
    const float CZ3 = -0.92387953251f, SZ3 = 0.38268343236f; // 7pi/8
    float f1[4];
    {
        float x;
        x = 0.5f + 0.5f * (cth * CZ0 + sth * SZ0);
        { float x2 = x * x, x4 = x2 * x2, x8 = x4 * x4, x16 = x8 * x8; f1[0] = x16 * x16; }
        x = 0.5f + 0.5f * (cth * CZ1 + sth * SZ1);
        { float x2 = x * x, x4 = x2 * x2, x8 = x4 * x4, x16 = x8 * x8; f1[1] = x16 * x16; }
        x = 0.5f + 0.5f * (cth * CZ2 + sth * SZ2);
        { float x2 = x * x, x4 = x2 * x2, x8 = x4 * x4, x16 = x8 * x8; f1[2] = x16 * x16; }
        x = 0.5f + 0.5f * (cth * CZ3 + sth * SZ3);
        { float x2 = x * x, x4 = x2 * x2, x8 = x4 * x4, x16 = x8 * x8; f1[3] = x16 * x16; }
    }

    float* base = out + (size_t)central[p] * OUTC + 144 + pair * 16;
#pragma unroll
    for (int a = 0; a < 4; ++a) {
        float da = d12 - (0.8f + 0.675f * (float)a);
        float f2 = __expf(-8.0f * da * da) * scale;
#pragma unroll
        for (int zz = 0; zz < 4; ++zz) {
            float v = f2 * f1[zz];
            if (v > 6e-7f) unsafeAtomicAdd(base + a * 4 + zz, v);
        }
    }
}

extern "C" void kernel_launch(void* const* d_in, const int* in_sizes, int n_in,
                              void* d_out, int out_size, void* d_ws, size_t ws_size,
                              hipStream_t stream) {
    const float* ecfp      = (const float*)d_in[0];
    const float* distances = (const float*)d_in[1];
    const float* sw        = (const float*)d_in[2];
    const float* angles    = (const float*)d_in[3];
    const float* angd      = (const float*)d_in[4];
    const float* angsw     = (const float*)d_in[5];
    const int*   species   = (const int*)d_in[6];
    const int*   bond_ord  = (const int*)d_in[7];
    const int*   edge_src  = (const int*)d_in[8];
    const int*   edge_dst  = (const int*)d_in[9];
    const int*   aedst     = (const int*)d_in[10];
    const int*   central   = (const int*)d_in[11];
    const int*   angle_src = (const int*)d_in[12];
    const int*   angle_dst = (const int*)d_in[13];
    float* out = (float*)d_out;

    const int e_rad   = in_sizes[1];
    const int n_pairs = in_sizes[3];
    const int n_atoms = in_sizes[6];

    int total4 = n_atoms * (OUTC / 4);
    k_init<<<(total4 + 255) / 256, 256, 0, stream>>>(ecfp, out, total4);
    k_radial<<<(e_rad + 255) / 256, 256, 0, stream>>>(distances, sw, bond_ord,
                                                      edge_src, edge_dst, species,
                                                      out, e_rad);
    k_ang<<<(n_pairs + 255) / 256, 256, 0, stream>>>(angles, angd, angsw, aedst,
                                                     species, central, angle_src,
                                                     angle_dst, out, n_pairs);
}

// Round 2
// 937.001 us; speedup vs baseline: 1.3978x; 1.3978x over previous
//
#include <hip/hip_runtime.h>
#include <math.h>

#define OUTC 304
#define AG 64   // atoms per accumulation block

// ---------------- ecfp copy: out[:,0:16] = ecfp ----------------
__global__ __launch_bounds__(256) void k_ecfp(const float* __restrict__ ecfp,
                                              float* __restrict__ out, int total4) {
    int i = blockIdx.x * 256 + threadIdx.x;   // float4 over (N,4)
    if (i >= total4) return;
    int row = i >> 2, c4 = i & 3;
    ((float4*)out)[row * (OUTC / 4) + c4] = ((const float4*)ecfp)[i];
}

// ---------------- zero int buffer ----------------
__global__ __launch_bounds__(256) void k_zero(int* __restrict__ a, int n) {
    int i = blockIdx.x * 256 + threadIdx.x;
    if (i < n) a[i] = 0;
}

// ---------------- histogram by key ----------------
__global__ __launch_bounds__(256) void k_hist(const int* __restrict__ keys,
                                              int* __restrict__ hist, int n) {
    int i = blockIdx.x * 256 + threadIdx.x;
    if (i < n) atomicAdd(&hist[keys[i]], 1);
}

// ---------------- single-block exclusive scan (n up to ~64k) ----------------
__global__ __launch_bounds__(1024) void k_scan(const int* __restrict__ hist,
                                               int* __restrict__ starts,
                                               int* __restrict__ offs, int n) {
    __shared__ int sums[1024];
    int tid = threadIdx.x;
    int C = (n + 1023) / 1024;
    int i0 = tid * C;
    int s = 0;
    for (int k = 0; k < C; ++k) { int i = i0 + k; if (i < n) s += hist[i]; }
    sums[tid] = s;
    __syncthreads();
    for (int d = 1; d < 1024; d <<= 1) {
        int t = (tid >= d) ? sums[tid - d] : 0;
        __syncthreads();
        sums[tid] += t;
        __syncthreads();
    }
    int run = sums[tid] - s;   // exclusive prefix for this chunk
    for (int k = 0; k < C; ++k) {
        int i = i0 + k;
        if (i < n) { int h = hist[i]; starts[i] = run; offs[i] = run; run += h; }
    }
    if (tid == 1023) starts[n] = sums[1023];
}

// ---------------- radial: scatter payload sorted by src atom ----------------
__global__ __launch_bounds__(256) void k_scatter_rad(const float* __restrict__ dist,
                                                     const float* __restrict__ sw,
                                                     const int* __restrict__ bond_order,
                                                     const int* __restrict__ esrc,
                                                     const int* __restrict__ edst,
                                                     const int* __restrict__ species,
                                                     int* __restrict__ offs,
                                                     float4* __restrict__ payload,
                                                     int e_rad) {
    int e = blockIdx.x * 256 + threadIdx.x;
    if (e >= e_rad) return;
    float d = dist[e];
    float coef = 0.25f * sw[e];
    int bo = bond_order[e];
    int bb = (bo == 3 || bo == 5) ? 1 : 0;       // weight<1 -> slot 1
    int z = species[edst[e]];
    int sp = (z == 6) ? 1 : (z == 7) ? 2 : (z == 8) ? 3 : 0;
    int c = esrc[e];
    int base = (c & (AG - 1)) * 129 + sp * 32 + bb;   // padded LDS layout
    int pos = atomicAdd(&offs[c], 1);
    payload[pos] = make_float4(d, coef, __int_as_float(base), 0.f);
}

// ---------------- radial: per-64-atom LDS accumulation ----------------
__global__ __launch_bounds__(256) void k_accum_rad(const float4* __restrict__ payload,
                                                   const int* __restrict__ starts,
                                                   float* __restrict__ out, int n_atoms) {
    __shared__ float acc[AG * 129];
    int a0 = blockIdx.x * AG;
    int aend = min(a0 + AG, n_atoms);
    for (int i = threadIdx.x; i < AG * 129; i += 256) acc[i] = 0.f;
    __syncthreads();
    int rs = starts[a0], re = starts[aend];
    for (int r = rs + threadIdx.x; r < re; r += 256) {
        float4 pl = payload[r];
        float d = pl.x, coef = pl.y;
        int base = __float_as_int(pl.z);
#pragma unroll
        for (int k = 0; k < 16; ++k) {
            float delta = d - (0.8f + 0.275f * (float)k);
            float v = coef * __expf(-16.0f * delta * delta);
            if (v > 1e-6f) atomicAdd(&acc[base + k * 2], v);
        }
    }
    __syncthreads();
    for (int i = threadIdx.x; i < AG * 128; i += 256) {
        int la = i >> 7, cc = i & 127;
        int atom = a0 + la;
        if (atom < n_atoms) out[(size_t)atom * OUTC + 16 + cc] = acc[la * 129 + cc];
    }
}

// ---------------- angular: scatter payload sorted by central atom ----------------
__global__ __launch_bounds__(256) void k_scatter_ang(const float* __restrict__ angles,
                                                     const float* __restrict__ angd,
                                                     const float* __restrict__ angsw,
                                                     const int* __restrict__ aedst,
                                                     const int* __restrict__ species,
                                                     const int* __restrict__ central,
                                                     const int* __restrict__ psrc,
                                                     const int* __restrict__ pdst,
                                                     int* __restrict__ offs,
                                                     float4* __restrict__ payload,
                                                     int n_pairs) {
    int p = blockIdx.x * 256 + threadIdx.x;
    if (p >= n_pairs) return;
    int is = psrc[p];
    int it = pdst[p];
    float d12 = 0.5f * (angd[is] + angd[it]);
    float scale = 2.0f * angsw[is] * angsw[it];
    int zs = species[aedst[is]];
    int zt = species[aedst[it]];
    int sps = (zs == 6) ? 1 : (zs == 7) ? 2 : (zs == 8) ? 3 : 0;
    int spt = (zt == 6) ? 1 : (zt == 7) ? 2 : (zt == 8) ? 3 : 0;
    int i = min(sps, spt), j = max(sps, spt);
    int pair = i * 4 - (i * (i - 1)) / 2 + (j - i);
    int c = central[p];
    int base = (c & (AG - 1)) * 161 + pair * 16;      // padded LDS layout
    int pos = atomicAdd(&offs[c], 1);
    payload[pos] = make_float4(angles[p], d12, scale, __int_as_float(base));
}

// ---------------- angular: per-64-atom LDS accumulation ----------------
__global__ __launch_bounds__(256) void k_accum_ang(const float4* __restrict__ payload,
                                                   const int* __restrict__ starts,
                                                   float* __restrict__ out, int n_atoms) {
    __shared__ float acc[AG * 161];
    int a0 = blockIdx.x * AG;
    int aend = min(a0 + AG, n_atoms);
    for (int i = threadIdx.x; i < AG * 161; i += 256) acc[i] = 0.f;
    __syncthreads();
    int rs = starts[a0], re = starts[aend];
    const float CZ[4] = {0.92387953251f, 0.38268343236f, -0.38268343236f, -0.92387953251f};
    const float SZ[4] = {0.38268343236f, 0.92387953251f, 0.92387953251f, 0.38268343236f};
    for (int r = rs + threadIdx.x; r < re; r += 256) {
        float4 pl = payload[r];
        float th = pl.x, d12 = pl.y, scale = pl.z;
        int base = __float_as_int(pl.w);
        float sth, cth;
        __sincosf(th, &sth, &cth);
        float f1[4];
#pragma unroll
        for (int zz = 0; zz < 4; ++zz) {
            float x = 0.5f + 0.5f * (cth * CZ[zz] + sth * SZ[zz]);
            float x2 = x * x, x4 = x2 * x2, x8 = x4 * x4, x16 = x8 * x8;
            f1[zz] = x16 * x16;
        }
#pragma unroll
        for (int a = 0; a < 4; ++a) {
            float da = d12 - (0.8f + 0.675f * (float)a);
            float f2 = __expf(-8.0f * da * da) * scale;
#pragma unroll
            for (int zz = 0; zz < 4; ++zz) {
                float v = f2 * f1[zz];
                if (v > 1e-6f) atomicAdd(&acc[base + a * 4 + zz], v);
            }
        }
    }
    __syncthreads();
    for (int i = threadIdx.x; i < AG * 160; i += 256) {
        int la = i / 160, cc = i - la * 160;
        int atom = a0 + la;
        if (atom < n_atoms) out[(size_t)atom * OUTC + 144 + cc] = acc[la * 161 + cc];
    }
}

// ================= fallback (round-1 atomic path) =================
__global__ __launch_bounds__(256) void k_init_fb(const float* __restrict__ ecfp,
                                                 float* __restrict__ out, int total4) {
    int i = blockIdx.x * 256 + threadIdx.x;
    if (i >= total4) return;
    int row = i / 76, c4 = i - row * 76;
    float4 v = make_float4(0.f, 0.f, 0.f, 0.f);
    if (c4 < 4) v = ((const float4*)ecfp)[row * 4 + c4];
    ((float4*)out)[i] = v;
}

__global__ __launch_bounds__(256) void k_radial_fb(const float* __restrict__ dist,
                                                   const float* __restrict__ sw,
                                                   const int* __restrict__ bond_order,
                                                   const int* __restrict__ esrc,
                                                   const int* __restrict__ edst,
                                                   const int* __restrict__ species,
                                                   float* __restrict__ out, int e_rad) {
    int e = blockIdx.x * 256 + threadIdx.x;
    if (e >= e_rad) return;
    float d = dist[e], s = sw[e];
    int bo = bond_order[e];
    int bb = (bo == 3 || bo == 5) ? 1 : 0;
    int z = species[edst[e]];
    int sp = (z == 6) ? 1 : (z == 7) ? 2 : (z == 8) ? 3 : 0;
    float* base = out + (size_t)esrc[e] * OUTC + 16 + sp * 32 + bb;
    float coef = 0.25f * s;
#pragma unroll
    for (int r = 0; r < 16; ++r) {
        float delta = d - (0.8f + 0.275f * (float)r);
        float v = coef * __expf(-16.0f * delta * delta);
        if (v > 6e-7f) unsafeAtomicAdd(base + r * 2, v);
    }
}

__global__ __launch_bounds__(256) void k_ang_fb(const float* __restrict__ angles,
                                                const float* __restrict__ angd,
                                                const float* __restrict__ angsw,
                                                const int* __restrict__ aedst,
                                                const int* __restrict__ species,
                                                const int* __restrict__ central,
                                                const int* __restrict__ psrc,
                                                const int* __restrict__ pdst,
                                                float* __restrict__ out, int n_pairs) {
    int p = blockIdx.x * 256 + threadIdx.x;
    if (p >= n_pairs) return;
    int is = psrc[p], it = pdst[p];
    float th = angles[p];
    float d12 = 0.5f * (angd[is] + angd[it]);
    float scale = 2.0f * angsw[is] * angsw[it];
    int zs = species[aedst[is]], zt = species[aedst[it]];
    int sps = (zs == 6) ? 1 : (zs == 7) ? 2 : (zs == 8) ? 3 : 0;
    int spt = (zt == 6) ? 1 : (zt == 7) ? 2 : (zt == 8) ? 3 : 0;
    int i = min(sps, spt), j = max(sps, spt);
    int pair = i * 4 - (i * (i - 1)) / 2 + (j - i);
    float sth, cth;
    __sincosf(th, &sth, &cth);
    const float CZ[4] = {0.92387953251f, 0.38268343236f, -0.38268343236f, -0.92387953251f};
    const float SZ[4] = {0.38268343236f, 0.92387953251f, 0.92387953251f, 0.38268343236f};
    float f1[4];
#pragma unroll
    for (int zz = 0; zz < 4; ++zz) {
        float x = 0.5f + 0.5f * (cth * CZ[zz] + sth * SZ[zz]);
        float x2 = x * x, x4 = x2 * x2, x8 = x4 * x4, x16 = x8 * x8;
        f1[zz] = x16 * x16;
    }
    float* base = out + (size_t)central[p] * OUTC + 144 + pair * 16;
#pragma unroll
    for (int a = 0; a < 4; ++a) {
        float da = d12 - (0.8f + 0.675f * (float)a);
        float f2 = __expf(-8.0f * da * da) * scale;
#pragma unroll
        for (int zz = 0; zz < 4; ++zz) {
            float v = f2 * f1[zz];
            if (v > 6e-7f) unsafeAtomicAdd(base + a * 4 + zz, v);
        }
    }
}

extern "C" void kernel_launch(void* const* d_in, const int* in_sizes, int n_in,
                              void* d_out, int out_size, void* d_ws, size_t ws_size,
                              hipStream_t stream) {
    const float* ecfp      = (const float*)d_in[0];
    const float* distances = (const float*)d_in[1];
    const float* sw        = (const float*)d_in[2];
    const float* angles    = (const float*)d_in[3];
    const float* angd      = (const float*)d_in[4];
    const float* angsw     = (const float*)d_in[5];
    const int*   species   = (const int*)d_in[6];
    const int*   bond_ord  = (const int*)d_in[7];
    const int*   edge_src  = (const int*)d_in[8];
    const int*   edge_dst  = (const int*)d_in[9];
    const int*   aedst     = (const int*)d_in[10];
    const int*   central   = (const int*)d_in[11];
    const int*   angle_src = (const int*)d_in[12];
    const int*   angle_dst = (const int*)d_in[13];
    float* out = (float*)d_out;

    const int e_rad   = in_sizes[1];
    const int n_pairs = in_sizes[3];
    const int n_atoms = in_sizes[6];

    const int emax = (e_rad > n_pairs) ? e_rad : n_pairs;
    size_t pay_bytes = (size_t)emax * 16;
    size_t meta_ints = (size_t)n_atoms * 3 + 1;   // hist, starts(n+1), offs
    size_t need = pay_bytes + meta_ints * 4;

    if (ws_size >= need) {
        float4* payload = (float4*)d_ws;
        int* hist   = (int*)((char*)d_ws + pay_bytes);
        int* starts = hist + n_atoms;          // n_atoms+1
        int* offs   = starts + n_atoms + 1;

        int gE   = (e_rad + 255) / 256;
        int gP   = (n_pairs + 255) / 256;
        int gA   = (n_atoms + 255) / 256;
        int gG   = (n_atoms + AG - 1) / AG;

        k_ecfp<<<(n_atoms * 4 + 255) / 256, 256, 0, stream>>>(ecfp, out, n_atoms * 4);

        // radial pipeline
        k_zero<<<gA, 256, 0, stream>>>(hist, n_atoms);
        k_hist<<<gE, 256, 0, stream>>>(edge_src, hist, e_rad);
        k_scan<<<1, 1024, 0, stream>>>(hist, starts, offs, n_atoms);
        k_scatter_rad<<<gE, 256, 0, stream>>>(distances, sw, bond_ord, edge_src,
                                              edge_dst, species, offs, payload, e_rad);
        k_accum_rad<<<gG, 256, 0, stream>>>(payload, starts, out, n_atoms);

        // angular pipeline (reuses payload/hist/starts/offs sequentially)
        k_zero<<<gA, 256, 0, stream>>>(hist, n_atoms);
        k_hist<<<gP, 256, 0, stream>>>(central, hist, n_pairs);
        k_scan<<<1, 1024, 0, stream>>>(hist, starts, offs, n_atoms);
        k_scatter_ang<<<gP, 256, 0, stream>>>(angles, angd, angsw, aedst, species,
                                              central, angle_src, angle_dst, offs,
                                              payload, n_pairs);
        k_accum_ang<<<gG, 256, 0, stream>>>(payload, starts, out, n_atoms);
    } else {
        // fallback: direct global-atomic path
        int total4 = n_atoms * (OUTC / 4);
        k_init_fb<<<(total4 + 255) / 256, 256, 0, stream>>>(ecfp, out, total4);
        k_radial_fb<<<(e_rad + 255) / 256, 256, 0, stream>>>(distances, sw, bond_ord,
                                                             edge_src, edge_dst, species,
                                                             out, e_rad);
        k_ang_fb<<<(n_pairs + 255) / 256, 256, 0, stream>>>(angles, angd, angsw, aedst,
                                                            species, central, angle_src,
                                                            angle_dst, out, n_pairs);
    }
}

// Round 3
// 575.616 us; speedup vs baseline: 2.2754x; 1.6278x over previous
//
#include <hip/hip_runtime.h>
#include <math.h>

#define OUTC 304
#define AG 64            // atoms per accumulation block
#define BIN_SH 4         // 16 atoms per sort bin
#define MAX_NB 3200      // LDS histogram capacity (bins)

// ---------------- ecfp copy: out[:,0:16] = ecfp ----------------
__global__ __launch_bounds__(256) void k_ecfp(const float* __restrict__ ecfp,
                                              float* __restrict__ out, int total4) {
    int i = blockIdx.x * 256 + threadIdx.x;   // float4 over (N,4)
    if (i >= total4) return;
    int row = i >> 2, c4 = i & 3;
    ((float4*)out)[row * (OUTC / 4) + c4] = ((const float4*)ecfp)[i];
}

// ---------------- zero int buffer ----------------
__global__ __launch_bounds__(256) void k_zero(int* __restrict__ a, int n) {
    int i = blockIdx.x * 256 + threadIdx.x;
    if (i < n) a[i] = 0;
}

// ---------------- angular edge records: (d, sw|sp) ----------------
__global__ __launch_bounds__(256) void k_prep_edge(const float* __restrict__ angd,
                                                   const float* __restrict__ angsw,
                                                   const int* __restrict__ aedst,
                                                   const int* __restrict__ species,
                                                   float2* __restrict__ erec, int n) {
    int i = blockIdx.x * 256 + threadIdx.x;
    if (i >= n) return;
    int z = species[aedst[i]];
    unsigned sp = (z == 6) ? 1u : (z == 7) ? 2u : (z == 8) ? 3u : 0u;
    unsigned swb = (__float_as_uint(angsw[i]) & ~3u) | sp;
    erec[i] = make_float2(angd[i], __uint_as_float(swb));
}

// ---------------- fused LDS-staged histogram (radial + angular) ----------------
__global__ __launch_bounds__(256) void k_hist2(const int* __restrict__ keysR, int nR,
                                               int* __restrict__ histR,
                                               const int* __restrict__ keysA, int nA,
                                               int* __restrict__ histA, int nb,
                                               int halfBlocks) {
    __shared__ int h[MAX_NB];
    for (int j = threadIdx.x; j < nb; j += 256) h[j] = 0;
    __syncthreads();
    bool ang = blockIdx.x >= halfBlocks;
    const int* keys = ang ? keysA : keysR;
    int n = ang ? nA : nR;
    int* hist = ang ? histA : histR;
    int b0 = ang ? (blockIdx.x - halfBlocks) : blockIdx.x;
    for (int i = b0 * 256 + threadIdx.x; i < n; i += halfBlocks * 256)
        atomicAdd(&h[keys[i] >> BIN_SH], 1);
    __syncthreads();
    for (int j = threadIdx.x; j < nb; j += 256) {
        int v = h[j];
        if (v) atomicAdd(&hist[j], v);
    }
}

// ---------------- dual single-block exclusive scan ----------------
__global__ __launch_bounds__(1024) void k_scan2(const int* __restrict__ histR,
                                                int* __restrict__ startsR,
                                                int* __restrict__ offsR,
                                                const int* __restrict__ histA,
                                                int* __restrict__ startsA,
                                                int* __restrict__ offsA, int n) {
    const int* hist = (blockIdx.x == 0) ? histR : histA;
    int* starts     = (blockIdx.x == 0) ? startsR : startsA;
    int* offs       = (blockIdx.x == 0) ? offsR : offsA;
    __shared__ int sums[1024];
    int tid = threadIdx.x;
    int C = (n + 1023) / 1024;
    int i0 = tid * C;
    int s = 0;
    for (int k = 0; k < C; ++k) { int i = i0 + k; if (i < n) s += hist[i]; }
    sums[tid] = s;
    __syncthreads();
    for (int d = 1; d < 1024; d <<= 1) {
        int t = (tid >= d) ? sums[tid - d] : 0;
        __syncthreads();
        sums[tid] += t;
        __syncthreads();
    }
    int run = sums[tid] - s;
    for (int k = 0; k < C; ++k) {
        int i = i0 + k;
        if (i < n) { int h = hist[i]; starts[i] = run; offs[i] = run; run += h; }
    }
    if (tid == 1023) starts[n] = run;
}

// ---------------- radial scatter: 8B packed payload, binned ----------------
__global__ __launch_bounds__(256) void k_scatter_rad(const float* __restrict__ dist,
                                                     const float* __restrict__ sw,
                                                     const int* __restrict__ bond_order,
                                                     const int* __restrict__ esrc,
                                                     const int* __restrict__ edst,
                                                     const int* __restrict__ species,
                                                     int* __restrict__ offs,
                                                     uint2* __restrict__ payload,
                                                     int e_rad) {
    int e = blockIdx.x * 256 + threadIdx.x;
    if (e >= e_rad) return;
    float d = dist[e];
    float s = sw[e];
    int bo = bond_order[e];
    unsigned bb = (bo == 3 || bo == 5) ? 1u : 0u;
    int z = species[edst[e]];
    unsigned sp = (z == 6) ? 1u : (z == 7) ? 2u : (z == 8) ? 3u : 0u;
    int c = esrc[e];
    unsigned dq = (unsigned)fminf((d - 0.8f) * (65535.0f / 4.4f) + 0.5f, 65535.0f);
    unsigned sq = (unsigned)fminf(s * 65535.0f + 0.5f, 65535.0f);
    unsigned loc = (unsigned)(c & (AG - 1));
    uint2 pl;
    pl.x = dq | (sq << 16);
    pl.y = loc | (sp << 6) | (bb << 8);
    int pos = atomicAdd(&offs[c >> BIN_SH], 1);
    payload[pos] = pl;
}

// ---------------- radial accumulate: per-64-atom LDS ----------------
__global__ __launch_bounds__(256) void k_accum_rad(const uint2* __restrict__ payload,
                                                   const int* __restrict__ starts,
                                                   float* __restrict__ out,
                                                   int n_atoms, int nb) {
    __shared__ float acc[AG * 129];
    int g = blockIdx.x;
    int a0 = g * AG;
    for (int i = threadIdx.x; i < AG * 129; i += 256) acc[i] = 0.f;
    __syncthreads();
    int b0 = g * 4;
    int rs = starts[b0];
    int re = starts[min(b0 + 4, nb)];
    for (int r = rs + threadIdx.x; r < re; r += 256) {
        uint2 pl = payload[r];
        float d = 0.8f + (float)(pl.x & 0xffffu) * (4.4f / 65535.0f);
        float coef = 0.25f * (float)(pl.x >> 16) * (1.0f / 65535.0f);
        int base = (int)(pl.y & 63u) * 129 + (int)((pl.y >> 6) & 3u) * 32 + (int)((pl.y >> 8) & 1u);
#pragma unroll
        for (int k = 0; k < 16; ++k) {
            float delta = d - (0.8f + 0.275f * (float)k);
            float v = coef * __expf(-16.0f * delta * delta);
            if (v > 1e-6f) atomicAdd(&acc[base + k * 2], v);
        }
    }
    __syncthreads();
    for (int i = threadIdx.x; i < AG * 128; i += 256) {
        int la = i >> 7, cc = i & 127;
        int atom = a0 + la;
        if (atom < n_atoms) out[(size_t)atom * OUTC + 16 + cc] = acc[la * 129 + cc];
    }
}

// ---------------- angular scatter: 8B packed payload, binned ----------------
__global__ __launch_bounds__(256) void k_scatter_ang(const float* __restrict__ angles,
                                                     const float2* __restrict__ erec,
                                                     const int* __restrict__ central,
                                                     const int* __restrict__ psrc,
                                                     const int* __restrict__ pdst,
                                                     int* __restrict__ offs,
                                                     uint2* __restrict__ payload,
                                                     int n_pairs) {
    int p = blockIdx.x * 256 + threadIdx.x;
    if (p >= n_pairs) return;
    float2 rs = erec[psrc[p]];
    float2 rt = erec[pdst[p]];
    unsigned us = __float_as_uint(rs.y), ut = __float_as_uint(rt.y);
    int sps = (int)(us & 3u), spt = (int)(ut & 3u);
    float ss = __uint_as_float(us & ~3u), st = __uint_as_float(ut & ~3u);
    int i = min(sps, spt), j = max(sps, spt);
    unsigned pair = (unsigned)(i * 4 - (i * (i - 1)) / 2 + (j - i));
    float d12 = 0.5f * (rs.x + rt.x);
    float scale = 2.0f * ss * st;
    float th = angles[p];
    int c = central[p];
    unsigned tq = (unsigned)fminf(th * (65535.0f / 3.14159265358979f) + 0.5f, 65535.0f);
    unsigned dq = (unsigned)fminf((d12 - 0.8f) * (65535.0f / 2.7f) + 0.5f, 65535.0f);
    unsigned sq = (unsigned)fminf(scale * (65535.0f / 2.0f) + 0.5f, 65535.0f);
    unsigned loc = (unsigned)(c & (AG - 1));
    uint2 pl;
    pl.x = tq | (dq << 16);
    pl.y = sq | (loc << 16) | (pair << 22);
    int pos = atomicAdd(&offs[c >> BIN_SH], 1);
    payload[pos] = pl;
}

// ---------------- angular accumulate: per-64-atom LDS ----------------
__global__ __launch_bounds__(256) void k_accum_ang(const uint2* __restrict__ payload,
                                                   const int* __restrict__ starts,
                                                   float* __restrict__ out,
                                                   int n_atoms, int nb) {
    __shared__ float acc[AG * 161];
    int g = blockIdx.x;
    int a0 = g * AG;
    for (int i = threadIdx.x; i < AG * 161; i += 256) acc[i] = 0.f;
    __syncthreads();
    int b0 = g * 4;
    int rsr = starts[b0];
    int rer = starts[min(b0 + 4, nb)];
    const float CZ[4] = {0.92387953251f, 0.38268343236f, -0.38268343236f, -0.92387953251f};
    const float SZ[4] = {0.38268343236f, 0.92387953251f, 0.92387953251f, 0.38268343236f};
    for (int r = rsr + threadIdx.x; r < rer; r += 256) {
        uint2 pl = payload[r];
        float th    = (float)(pl.x & 0xffffu) * (3.14159265358979f / 65535.0f);
        float d12   = 0.8f + (float)(pl.x >> 16) * (2.7f / 65535.0f);
        float scale = (float)(pl.y & 0xffffu) * (2.0f / 65535.0f);
        int base = (int)((pl.y >> 16) & 63u) * 161 + (int)((pl.y >> 22) & 15u) * 16;
        float sth, cth;
        __sincosf(th, &sth, &cth);
        float f1[4];
#pragma unroll
        for (int zz = 0; zz < 4; ++zz) {
            float x = 0.5f + 0.5f * (cth * CZ[zz] + sth * SZ[zz]);
            float x2 = x * x, x4 = x2 * x2, x8 = x4 * x4, x16 = x8 * x8;
            f1[zz] = x16 * x16;
        }
#pragma unroll
        for (int a = 0; a < 4; ++a) {
            float da = d12 - (0.8f + 0.675f * (float)a);
            float f2 = __expf(-8.0f * da * da) * scale;
#pragma unroll
            for (int zz = 0; zz < 4; ++zz) {
                float v = f2 * f1[zz];
                if (v > 1e-6f) atomicAdd(&acc[base + a * 4 + zz], v);
            }
        }
    }
    __syncthreads();
    for (int i = threadIdx.x; i < AG * 160; i += 256) {
        int la = i / 160, cc = i - la * 160;
        int atom = a0 + la;
        if (atom < n_atoms) out[(size_t)atom * OUTC + 144 + cc] = acc[la * 161 + cc];
    }
}

// ================= fallback (round-1 atomic path) =================
__global__ __launch_bounds__(256) void k_init_fb(const float* __restrict__ ecfp,
                                                 float* __restrict__ out, int total4) {
    int i = blockIdx.x * 256 + threadIdx.x;
    if (i >= total4) return;
    int row = i / 76, c4 = i - row * 76;
    float4 v = make_float4(0.f, 0.f, 0.f, 0.f);
    if (c4 < 4) v = ((const float4*)ecfp)[row * 4 + c4];
    ((float4*)out)[i] = v;
}

__global__ __launch_bounds__(256) void k_radial_fb(const float* __restrict__ dist,
                                                   const float* __restrict__ sw,
                                                   const int* __restrict__ bond_order,
                                                   const int* __restrict__ esrc,
                                                   const int* __restrict__ edst,
                                                   const int* __restrict__ species,
                                                   float* __restrict__ out, int e_rad) {
    int e = blockIdx.x * 256 + threadIdx.x;
    if (e >= e_rad) return;
    float d = dist[e], s = sw[e];
    int bo = bond_order[e];
    int bb = (bo == 3 || bo == 5) ? 1 : 0;
    int z = species[edst[e]];
    int sp = (z == 6) ? 1 : (z == 7) ? 2 : (z == 8) ? 3 : 0;
    float* base = out + (size_t)esrc[e] * OUTC + 16 + sp * 32 + bb;
    float coef = 0.25f * s;
#pragma unroll
    for (int r = 0; r < 16; ++r) {
        float delta = d - (0.8f + 0.275f * (float)r);
        float v = coef * __expf(-16.0f * delta * delta);
        if (v > 6e-7f) unsafeAtomicAdd(base + r * 2, v);
    }
}

__global__ __launch_bounds__(256) void k_ang_fb(const float* __restrict__ angles,
                                                const float* __restrict__ angd,
                                                const float* __restrict__ angsw,
                                                const int* __restrict__ aedst,
                                                const int* __restrict__ species,
                                                const int* __restrict__ central,
                                                const int* __restrict__ psrc,
                                                const int* __restrict__ pdst,
                                                float* __restrict__ out, int n_pairs) {
    int p = blockIdx.x * 256 + threadIdx.x;
    if (p >= n_pairs) return;
    int is = psrc[p], it = pdst[p];
    float th = angles[p];
    float d12 = 0.5f * (angd[is] + angd[it]);
    float scale = 2.0f * angsw[is] * angsw[it];
    int zs = species[aedst[is]], zt = species[aedst[it]];
    int sps = (zs == 6) ? 1 : (zs == 7) ? 2 : (zs == 8) ? 3 : 0;
    int spt = (zt == 6) ? 1 : (zt == 7) ? 2 : (zt == 8) ? 3 : 0;
    int i = min(sps, spt), j = max(sps, spt);
    int pair = i * 4 - (i * (i - 1)) / 2 + (j - i);
    float sth, cth;
    __sincosf(th, &sth, &cth);
    const float CZ[4] = {0.92387953251f, 0.38268343236f, -0.38268343236f, -0.92387953251f};
    const float SZ[4] = {0.38268343236f, 0.92387953251f, 0.92387953251f, 0.38268343236f};
    float f1[4];
#pragma unroll
    for (int zz = 0; zz < 4; ++zz) {
        float x = 0.5f + 0.5f * (cth * CZ[zz] + sth * SZ[zz]);
        float x2 = x * x, x4 = x2 * x2, x8 = x4 * x4, x16 = x8 * x8;
        f1[zz] = x16 * x16;
    }
    float* base = out + (size_t)central[p] * OUTC + 144 + pair * 16;
#pragma unroll
    for (int a = 0; a < 4; ++a) {
        float da = d12 - (0.8f + 0.675f * (float)a);
        float f2 = __expf(-8.0f * da * da) * scale;
#pragma unroll
        for (int zz = 0; zz < 4; ++zz) {
            float v = f2 * f1[zz];
            if (v > 6e-7f) unsafeAtomicAdd(base + a * 4 + zz, v);
        }
    }
}

extern "C" void kernel_launch(void* const* d_in, const int* in_sizes, int n_in,
                              void* d_out, int out_size, void* d_ws, size_t ws_size,
                              hipStream_t stream) {
    const float* ecfp      = (const float*)d_in[0];
    const float* distances = (const float*)d_in[1];
    const float* sw        = (const float*)d_in[2];
    const float* angles    = (const float*)d_in[3];
    const float* angd      = (const float*)d_in[4];
    const float* angsw     = (const float*)d_in[5];
    const int*   species   = (const int*)d_in[6];
    const int*   bond_ord  = (const int*)d_in[7];
    const int*   edge_src  = (const int*)d_in[8];
    const int*   edge_dst  = (const int*)d_in[9];
    const int*   aedst     = (const int*)d_in[10];
    const int*   central   = (const int*)d_in[11];
    const int*   angle_src = (const int*)d_in[12];
    const int*   angle_dst = (const int*)d_in[13];
    float* out = (float*)d_out;

    const int e_rad   = in_sizes[1];
    const int n_pairs = in_sizes[3];
    const int e_ang   = in_sizes[4];
    const int n_atoms = in_sizes[6];

    const int NB = (n_atoms + (1 << BIN_SH) - 1) >> BIN_SH;
    const int G  = (n_atoms + AG - 1) / AG;
    const int emax = (e_rad > n_pairs) ? e_rad : n_pairs;

    size_t pay_bytes  = (size_t)emax * 8;
    size_t erec_bytes = (size_t)e_ang * 8;
    size_t meta_ints  = (size_t)(3 * NB + 1) * 2;
    size_t need = pay_bytes + erec_bytes + meta_ints * 4;

    if (ws_size >= need && NB <= MAX_NB) {
        uint2*  payload = (uint2*)d_ws;
        float2* erec    = (float2*)((char*)d_ws + pay_bytes);
        int* histR   = (int*)((char*)erec + erec_bytes);
        int* startsR = histR + NB;           // NB+1
        int* offsR   = startsR + NB + 1;
        int* histA   = offsR + NB;
        int* startsA = histA + NB;           // NB+1
        int* offsA   = startsA + NB + 1;

        int gE = (e_rad + 255) / 256;
        int gP = (n_pairs + 255) / 256;

        k_ecfp<<<(n_atoms * 4 + 255) / 256, 256, 0, stream>>>(ecfp, out, n_atoms * 4);
        k_zero<<<(2 * NB + 255) / 256, 256, 0, stream>>>(histR, 2 * NB + 2);  // histR..startsR gap ok: zero both hists region? separate:
        // (histR[NB], startsR[NB+1], offsR[NB], histA[NB], ...) — zero only hists:
        k_zero<<<(NB + 255) / 256, 256, 0, stream>>>(histA, NB);
        k_prep_edge<<<(e_ang + 255) / 256, 256, 0, stream>>>(angd, angsw, aedst,
                                                             species, erec, e_ang);
        k_hist2<<<256, 256, 0, stream>>>(edge_src, e_rad, histR,
                                         central, n_pairs, histA, NB, 128);
        k_scan2<<<2, 1024, 0, stream>>>(histR, startsR, offsR, histA, startsA, offsA, NB);

        k_scatter_rad<<<gE, 256, 0, stream>>>(distances, sw, bond_ord, edge_src,
                                              edge_dst, species, offsR, payload, e_rad);
        k_accum_rad<<<G, 256, 0, stream>>>(payload, startsR, out, n_atoms, NB);

        k_scatter_ang<<<gP, 256, 0, stream>>>(angles, erec, central, angle_src,
                                              angle_dst, offsA, payload, n_pairs);
        k_accum_ang<<<G, 256, 0, stream>>>(payload, startsA, out, n_atoms, NB);
    } else {
        int total4 = n_atoms * (OUTC / 4);
        k_init_fb<<<(total4 + 255) / 256, 256, 0, stream>>>(ecfp, out, total4);
        k_radial_fb<<<(e_rad + 255) / 256, 256, 0, stream>>>(distances, sw, bond_ord,
                                                             edge_src, edge_dst, species,
                                                             out, e_rad);
        k_ang_fb<<<(n_pairs + 255) / 256, 256, 0, stream>>>(angles, angd, angsw, aedst,
                                                            species, central, angle_src,
                                                            angle_dst, out, n_pairs);
    }
}

// Round 4
// 405.633 us; speedup vs baseline: 3.2289x; 1.4191x over previous
//
#include <hip/hip_runtime.h>
#include <math.h>

#define OUTC 304
#define AG 64            // atoms per accumulation block
#define BIN_SH 5         // 32 atoms per bin
#define NSUB 8           // sub-buckets per bin (~XCD-local via blockIdx&7)
#define CAPX 256         // slots per (bin,sub); lambda=160 at 2M keys/50k atoms
#define OVF_CAP 65536

// ---------------- ecfp copy: out[:,0:16] = ecfp ----------------
__global__ __launch_bounds__(256) void k_ecfp(const float* __restrict__ ecfp,
                                              float* __restrict__ out, int total4) {
    int i = blockIdx.x * 256 + threadIdx.x;   // float4 over (N,4)
    if (i >= total4) return;
    int row = i >> 2, c4 = i & 3;
    ((float4*)out)[row * (OUTC / 4) + c4] = ((const float4*)ecfp)[i];
}

__global__ __launch_bounds__(256) void k_zero(int* __restrict__ a, int n) {
    int i = blockIdx.x * 256 + threadIdx.x;
    if (i < n) a[i] = 0;
}

// ---------------- angular edge records: d12b | sw14b | sp2b ----------------
__global__ __launch_bounds__(256) void k_prep_edge(const float* __restrict__ angd,
                                                   const float* __restrict__ angsw,
                                                   const int* __restrict__ aedst,
                                                   const int* __restrict__ species,
                                                   unsigned* __restrict__ erec, int n) {
    int i = blockIdx.x * 256 + threadIdx.x;
    if (i >= n) return;
    int z = species[aedst[i]];
    unsigned sp = (z == 6) ? 1u : (z == 7) ? 2u : (z == 8) ? 3u : 0u;
    float d = angd[i], s = angsw[i];
    unsigned dq = (unsigned)fminf(fmaxf((d - 0.8f) * (4095.0f / 2.7f) + 0.5f, 0.f), 4095.f);
    unsigned sq = (unsigned)fminf(fmaxf(s * 16383.0f + 0.5f, 0.f), 16383.f);
    erec[i] = dq | (sq << 12) | (sp << 26);
}

// ---------------- radial scatter into (bin,sub) buckets ----------------
__global__ __launch_bounds__(256) void k_scatter_rad(const float* __restrict__ dist,
                                                     const float* __restrict__ sw,
                                                     const int* __restrict__ bond_order,
                                                     const int* __restrict__ esrc,
                                                     const int* __restrict__ edst,
                                                     const int* __restrict__ species,
                                                     int* __restrict__ cnt,
                                                     uint2* __restrict__ payload,
                                                     uint4* __restrict__ ovf,
                                                     int* __restrict__ ovfc,
                                                     int e_rad) {
    int e = blockIdx.x * 256 + threadIdx.x;
    if (e >= e_rad) return;
    float d = dist[e];
    float s = sw[e];
    int bo = bond_order[e];
    unsigned bb = (bo == 3 || bo == 5) ? 1u : 0u;
    int z = species[edst[e]];
    unsigned sp = (z == 6) ? 1u : (z == 7) ? 2u : (z == 8) ? 3u : 0u;
    int c = esrc[e];
    unsigned dq = (unsigned)fminf(fmaxf((d - 0.8f) * (65535.0f / 4.4f) + 0.5f, 0.f), 65535.f);
    unsigned sq = (unsigned)fminf(fmaxf(s * 65535.0f + 0.5f, 0.f), 65535.f);
    uint2 pl;
    pl.x = dq | (sq << 16);
    pl.y = (unsigned)(c & (AG - 1)) | (sp << 6) | (bb << 8);
    int bs = (c >> BIN_SH) * NSUB + (blockIdx.x & (NSUB - 1));
    int slot = atomicAdd(&cnt[bs], 1);
    if (slot < CAPX) {
        payload[bs * CAPX + slot] = pl;
    } else {
        int oi = atomicAdd(ovfc, 1);
        if (oi < OVF_CAP) ovf[oi] = make_uint4(pl.x, pl.y, (unsigned)c, 0u);
    }
}

// ---------------- radial accumulate: per-64-atom LDS ----------------
__global__ __launch_bounds__(256) void k_accum_rad(const uint2* __restrict__ payload,
                                                   const int* __restrict__ cnt,
                                                   float* __restrict__ out,
                                                   int n_atoms, int nb) {
    __shared__ float acc[AG * 129];
    __shared__ int sbase[16], spre[17];
    int g = blockIdx.x;
    int a0 = g * AG;
    for (int i = threadIdx.x; i < AG * 129; i += 256) acc[i] = 0.f;
    if (threadIdx.x < 16) {
        int bin = 2 * g + (threadIdx.x >> 3);
        int sub = threadIdx.x & 7;
        int len = 0, base = 0;
        if (bin < nb) {
            int bs = bin * NSUB + sub;
            base = bs * CAPX;
            len = min(cnt[bs], CAPX);
        }
        sbase[threadIdx.x] = base;
        spre[threadIdx.x] = len;
    }
    __syncthreads();
    if (threadIdx.x == 0) {
        int run = 0;
        for (int s2 = 0; s2 < 16; ++s2) { int l = spre[s2]; spre[s2] = run; run += l; }
        spre[16] = run;
    }
    __syncthreads();
    int T = spre[16];
    for (int t = threadIdx.x; t < T; t += 256) {
        int s2 = 0;
#pragma unroll
        for (int k = 1; k < 16; ++k) s2 += (t >= spre[k]);
        uint2 pl = payload[sbase[s2] + (t - spre[s2])];
        float d = 0.8f + (float)(pl.x & 0xffffu) * (4.4f / 65535.0f);
        float coef = 0.25f * (float)(pl.x >> 16) * (1.0f / 65535.0f);
        int base = (int)(pl.y & 63u) * 129 + (int)((pl.y >> 6) & 3u) * 32 + (int)((pl.y >> 8) & 1u);
#pragma unroll
        for (int k = 0; k < 16; ++k) {
            float delta = d - (0.8f + 0.275f * (float)k);
            float v = coef * __expf(-16.0f * delta * delta);
            if (v > 1e-6f) atomicAdd(&acc[base + k * 2], v);
        }
    }
    __syncthreads();
    for (int i = threadIdx.x; i < AG * 128; i += 256) {
        int la = i >> 7, cc = i & 127;
        int atom = a0 + la;
        if (atom < n_atoms) out[(size_t)atom * OUTC + 16 + cc] = acc[la * 129 + cc];
    }
}

// ---------------- angular scatter into (bin,sub) buckets ----------------
__global__ __launch_bounds__(256) void k_scatter_ang(const float* __restrict__ angles,
                                                     const unsigned* __restrict__ erec,
                                                     const int* __restrict__ central,
                                                     const int* __restrict__ psrc,
                                                     const int* __restrict__ pdst,
                                                     int* __restrict__ cnt,
                                                     uint2* __restrict__ payload,
                                                     uint4* __restrict__ ovf,
                                                     int* __restrict__ ovfc,
                                                     int n_pairs) {
    int p = blockIdx.x * 256 + threadIdx.x;
    if (p >= n_pairs) return;
    unsigned rs = erec[psrc[p]];
    unsigned rt = erec[pdst[p]];
    float dsrc = 0.8f + (float)(rs & 0xfffu) * (2.7f / 4095.0f);
    float dtgt = 0.8f + (float)(rt & 0xfffu) * (2.7f / 4095.0f);
    float ss = (float)((rs >> 12) & 0x3fffu) * (1.0f / 16383.0f);
    float st = (float)((rt >> 12) & 0x3fffu) * (1.0f / 16383.0f);
    int sps = (int)(rs >> 26), spt = (int)(rt >> 26);
    int i = min(sps, spt), j = max(sps, spt);
    unsigned pair = (unsigned)(i * 4 - (i * (i - 1)) / 2 + (j - i));
    float d12 = 0.5f * (dsrc + dtgt);
    float scale = 2.0f * ss * st;
    float th = angles[p];
    int c = central[p];
    unsigned tq = (unsigned)fminf(fmaxf(th * (65535.0f / 3.14159265358979f) + 0.5f, 0.f), 65535.f);
    unsigned dq = (unsigned)fminf(fmaxf((d12 - 0.8f) * (65535.0f / 2.7f) + 0.5f, 0.f), 65535.f);
    unsigned sq = (unsigned)fminf(fmaxf(scale * (65535.0f / 2.0f) + 0.5f, 0.f), 65535.f);
    uint2 pl;
    pl.x = tq | (dq << 16);
    pl.y = sq | ((unsigned)(c & (AG - 1)) << 16) | (pair << 22);
    int bs = (c >> BIN_SH) * NSUB + (blockIdx.x & (NSUB - 1));
    int slot = atomicAdd(&cnt[bs], 1);
    if (slot < CAPX) {
        payload[bs * CAPX + slot] = pl;
    } else {
        int oi = atomicAdd(ovfc, 1);
        if (oi < OVF_CAP) ovf[oi] = make_uint4(pl.x, pl.y, (unsigned)c, 1u);
    }
}

// ---------------- angular accumulate: per-64-atom LDS ----------------
__global__ __launch_bounds__(256) void k_accum_ang(const uint2* __restrict__ payload,
                                                   const int* __restrict__ cnt,
                                                   float* __restrict__ out,
                                                   int n_atoms, int nb) {
    __shared__ float acc[AG * 161];
    __shared__ int sbase[16], spre[17];
    int g = blockIdx.x;
    int a0 = g * AG;
    for (int i = threadIdx.x; i < AG * 161; i += 256) acc[i] = 0.f;
    if (threadIdx.x < 16) {
        int bin = 2 * g + (threadIdx.x >> 3);
        int sub = threadIdx.x & 7;
        int len = 0, base = 0;
        if (bin < nb) {
            int bs = bin * NSUB + sub;
            base = bs * CAPX;
            len = min(cnt[bs], CAPX);
        }
        sbase[threadIdx.x] = base;
        spre[threadIdx.x] = len;
    }
    __syncthreads();
    if (threadIdx.x == 0) {
        int run = 0;
        for (int s2 = 0; s2 < 16; ++s2) { int l = spre[s2]; spre[s2] = run; run += l; }
        spre[16] = run;
    }
    __syncthreads();
    const float CZ[4] = {0.92387953251f, 0.38268343236f, -0.38268343236f, -0.92387953251f};
    const float SZ[4] = {0.38268343236f, 0.92387953251f, 0.92387953251f, 0.38268343236f};
    int T = spre[16];
    for (int t = threadIdx.x; t < T; t += 256) {
        int s2 = 0;
#pragma unroll
        for (int k = 1; k < 16; ++k) s2 += (t >= spre[k]);
        uint2 pl = payload[sbase[s2] + (t - spre[s2])];
        float th    = (float)(pl.x & 0xffffu) * (3.14159265358979f / 65535.0f);
        float d12   = 0.8f + (float)(pl.x >> 16) * (2.7f / 65535.0f);
        float scale = (float)(pl.y & 0xffffu) * (2.0f / 65535.0f);
        int base = (int)((pl.y >> 16) & 63u) * 161 + (int)((pl.y >> 22) & 15u) * 16;
        float sth, cth;
        __sincosf(th, &sth, &cth);
        float f1[4];
#pragma unroll
        for (int zz = 0; zz < 4; ++zz) {
            float x = 0.5f + 0.5f * (cth * CZ[zz] + sth * SZ[zz]);
            float x2 = x * x, x4 = x2 * x2, x8 = x4 * x4, x16 = x8 * x8;
            f1[zz] = x16 * x16;
        }
#pragma unroll
        for (int a = 0; a < 4; ++a) {
            float da = d12 - (0.8f + 0.675f * (float)a);
            float f2 = __expf(-8.0f * da * da) * scale;
#pragma unroll
            for (int zz = 0; zz < 4; ++zz) {
                float v = f2 * f1[zz];
                if (v > 1e-6f) atomicAdd(&acc[base + a * 4 + zz], v);
            }
        }
    }
    __syncthreads();
    for (int i = threadIdx.x; i < AG * 160; i += 256) {
        int la = i / 160, cc = i - la * 160;
        int atom = a0 + la;
        if (atom < n_atoms) out[(size_t)atom * OUTC + 144 + cc] = acc[la * 161 + cc];
    }
}

// ---------------- overflow spill: direct global atomics (rare/never) ----------------
__global__ __launch_bounds__(256) void k_spill(const uint4* __restrict__ ovf,
                                               const int* __restrict__ ovfc,
                                               float* __restrict__ out) {
    int n = min(*ovfc, OVF_CAP);
    const float CZ[4] = {0.92387953251f, 0.38268343236f, -0.38268343236f, -0.92387953251f};
    const float SZ[4] = {0.38268343236f, 0.92387953251f, 0.92387953251f, 0.38268343236f};
    for (int idx = blockIdx.x * 256 + threadIdx.x; idx < n; idx += gridDim.x * 256) {
        uint4 e = ovf[idx];
        if (e.w == 0u) {   // radial
            float d = 0.8f + (float)(e.x & 0xffffu) * (4.4f / 65535.0f);
            float coef = 0.25f * (float)(e.x >> 16) * (1.0f / 65535.0f);
            int sp = (int)((e.y >> 6) & 3u), bb = (int)((e.y >> 8) & 1u);
            float* base = out + (size_t)e.z * OUTC + 16 + sp * 32 + bb;
            for (int k = 0; k < 16; ++k) {
                float delta = d - (0.8f + 0.275f * (float)k);
                float v = coef * __expf(-16.0f * delta * delta);
                if (v > 1e-6f) unsafeAtomicAdd(base + k * 2, v);
            }
        } else {           // angular
            float th    = (float)(e.x & 0xffffu) * (3.14159265358979f / 65535.0f);
            float d12   = 0.8f + (float)(e.x >> 16) * (2.7f / 65535.0f);
            float scale = (float)(e.y & 0xffffu) * (2.0f / 65535.0f);
            int pair = (int)((e.y >> 22) & 15u);
            float* base = out + (size_t)e.z * OUTC + 144 + pair * 16;
            float sth, cth;
            __sincosf(th, &sth, &cth);
            for (int zz = 0; zz < 4; ++zz) {
                float x = 0.5f + 0.5f * (cth * CZ[zz] + sth * SZ[zz]);
                float x2 = x * x, x4 = x2 * x2, x8 = x4 * x4, x16 = x8 * x8;
                float f1 = x16 * x16;
                for (int a = 0; a < 4; ++a) {
                    float da = d12 - (0.8f + 0.675f * (float)a);
                    float v = __expf(-8.0f * da * da) * scale * f1;
                    if (v > 1e-6f) unsafeAtomicAdd(base + a * 4 + zz, v);
                }
            }
        }
    }
}

// ================= fallback (round-1 atomic path) =================
__global__ __launch_bounds__(256) void k_init_fb(const float* __restrict__ ecfp,
                                                 float* __restrict__ out, int total4) {
    int i = blockIdx.x * 256 + threadIdx.x;
    if (i >= total4) return;
    int row = i / 76, c4 = i - row * 76;
    float4 v = make_float4(0.f, 0.f, 0.f, 0.f);
    if (c4 < 4) v = ((const float4*)ecfp)[row * 4 + c4];
    ((float4*)out)[i] = v;
}

__global__ __launch_bounds__(256) void k_radial_fb(const float* __restrict__ dist,
                                                   const float* __restrict__ sw,
                                                   const int* __restrict__ bond_order,
                                                   const int* __restrict__ esrc,
                                                   const int* __restrict__ edst,
                                                   const int* __restrict__ species,
                                                   float* __restrict__ out, int e_rad) {
    int e = blockIdx.x * 256 + threadIdx.x;
    if (e >= e_rad) return;
    float d = dist[e], s = sw[e];
    int bo = bond_order[e];
    int bb = (bo == 3 || bo == 5) ? 1 : 0;
    int z = species[edst[e]];
    int sp = (z == 6) ? 1 : (z == 7) ? 2 : (z == 8) ? 3 : 0;
    float* base = out + (size_t)esrc[e] * OUTC + 16 + sp * 32 + bb;
    float coef = 0.25f * s;
#pragma unroll
    for (int r = 0; r < 16; ++r) {
        float delta = d - (0.8f + 0.275f * (float)r);
        float v = coef * __expf(-16.0f * delta * delta);
        if (v > 6e-7f) unsafeAtomicAdd(base + r * 2, v);
    }
}

__global__ __launch_bounds__(256) void k_ang_fb(const float* __restrict__ angles,
                                                const float* __restrict__ angd,
                                                const float* __restrict__ angsw,
                                                const int* __restrict__ aedst,
                                                const int* __restrict__ species,
                                                const int* __restrict__ central,
                                                const int* __restrict__ psrc,
                                                const int* __restrict__ pdst,
                                                float* __restrict__ out, int n_pairs) {
    int p = blockIdx.x * 256 + threadIdx.x;
    if (p >= n_pairs) return;
    int is = psrc[p], it = pdst[p];
    float th = angles[p];
    float d12 = 0.5f * (angd[is] + angd[it]);
    float scale = 2.0f * angsw[is] * angsw[it];
    int zs = species[aedst[is]], zt = species[aedst[it]];
    int sps = (zs == 6) ? 1 : (zs == 7) ? 2 : (zs == 8) ? 3 : 0;
    int spt = (zt == 6) ? 1 : (zt == 7) ? 2 : (zt == 8) ? 3 : 0;
    int i = min(sps, spt), j = max(sps, spt);
    int pair = i * 4 - (i * (i - 1)) / 2 + (j - i);
    float sth, cth;
    __sincosf(th, &sth, &cth);
    const float CZ[4] = {0.92387953251f, 0.38268343236f, -0.38268343236f, -0.92387953251f};
    const float SZ[4] = {0.38268343236f, 0.92387953251f, 0.92387953251f, 0.38268343236f};
    float f1[4];
#pragma unroll
    for (int zz = 0; zz < 4; ++zz) {
        float x = 0.5f + 0.5f * (cth * CZ[zz] + sth * SZ[zz]);
        float x2 = x * x, x4 = x2 * x2, x8 = x4 * x4, x16 = x8 * x8;
        f1[zz] = x16 * x16;
    }
    float* base = out + (size_t)central[p] * OUTC + 144 + pair * 16;
#pragma unroll
    for (int a = 0; a < 4; ++a) {
        float da = d12 - (0.8f + 0.675f * (float)a);
        float f2 = __expf(-8.0f * da * da) * scale;
#pragma unroll
        for (int zz = 0; zz < 4; ++zz) {
            float v = f2 * f1[zz];
            if (v > 6e-7f) unsafeAtomicAdd(base + a * 4 + zz, v);
        }
    }
}

extern "C" void kernel_launch(void* const* d_in, const int* in_sizes, int n_in,
                              void* d_out, int out_size, void* d_ws, size_t ws_size,
                              hipStream_t stream) {
    const float* ecfp      = (const float*)d_in[0];
    const float* distances = (const float*)d_in[1];
    const float* sw        = (const float*)d_in[2];
    const float* angles    = (const float*)d_in[3];
    const float* angd      = (const float*)d_in[4];
    const float* angsw     = (const float*)d_in[5];
    const int*   species   = (const int*)d_in[6];
    const int*   bond_ord  = (const int*)d_in[7];
    const int*   edge_src  = (const int*)d_in[8];
    const int*   edge_dst  = (const int*)d_in[9];
    const int*   aedst     = (const int*)d_in[10];
    const int*   central   = (const int*)d_in[11];
    const int*   angle_src = (const int*)d_in[12];
    const int*   angle_dst = (const int*)d_in[13];
    float* out = (float*)d_out;

    const int e_rad   = in_sizes[1];
    const int n_pairs = in_sizes[3];
    const int e_ang   = in_sizes[4];
    const int n_atoms = in_sizes[6];

    const int NB  = (n_atoms + (1 << BIN_SH) - 1) >> BIN_SH;
    const int NSB = NB * NSUB;
    const int G   = (n_atoms + AG - 1) / AG;

    size_t pay_bytes  = (size_t)NSB * CAPX * 8;
    size_t erec_bytes = (size_t)e_ang * 4;
    // pad erec region to 16B multiple for uint4 ovf alignment
    size_t erec_pad   = (erec_bytes + 15) & ~(size_t)15;
    size_t ovf_bytes  = (size_t)OVF_CAP * 16;
    size_t need = pay_bytes + erec_pad + ovf_bytes + (size_t)(2 * NSB + 4) * 4;

    bool cap_ok = (e_rad  <= (size_t)NSB * (CAPX * 3 / 4)) &&
                  (n_pairs <= (size_t)NSB * (CAPX * 3 / 4));

    if (ws_size >= need && cap_ok) {
        uint2*    payload = (uint2*)d_ws;
        unsigned* erec    = (unsigned*)((char*)d_ws + pay_bytes);
        uint4*    ovf     = (uint4*)((char*)d_ws + pay_bytes + erec_pad);
        int*      cntR    = (int*)((char*)ovf + ovf_bytes);
        int*      cntA    = cntR + NSB;
        int*      ovfc    = cntA + NSB;

        int gE = (e_rad + 255) / 256;
        int gP = (n_pairs + 255) / 256;

        k_ecfp<<<(n_atoms * 4 + 255) / 256, 256, 0, stream>>>(ecfp, out, n_atoms * 4);
        k_zero<<<(2 * NSB + 4 + 255) / 256, 256, 0, stream>>>(cntR, 2 * NSB + 4);
        k_prep_edge<<<(e_ang + 255) / 256, 256, 0, stream>>>(angd, angsw, aedst,
                                                             species, erec, e_ang);
        k_scatter_rad<<<gE, 256, 0, stream>>>(distances, sw, bond_ord, edge_src,
                                              edge_dst, species, cntR, payload,
                                              ovf, ovfc, e_rad);
        k_accum_rad<<<G, 256, 0, stream>>>(payload, cntR, out, n_atoms, NB);
        k_scatter_ang<<<gP, 256, 0, stream>>>(angles, erec, central, angle_src,
                                              angle_dst, cntA, payload,
                                              ovf, ovfc, n_pairs);
        k_accum_ang<<<G, 256, 0, stream>>>(payload, cntA, out, n_atoms, NB);
        k_spill<<<16, 256, 0, stream>>>(ovf, ovfc, out);
    } else {
        int total4 = n_atoms * (OUTC / 4);
        k_init_fb<<<(total4 + 255) / 256, 256, 0, stream>>>(ecfp, out, total4);
        k_radial_fb<<<(e_rad + 255) / 256, 256, 0, stream>>>(distances, sw, bond_ord,
                                                             edge_src, edge_dst, species,
                                                             out, e_rad);
        k_ang_fb<<<(n_pairs + 255) / 256, 256, 0, stream>>>(angles, angd, angsw, aedst,
                                                            species, central, angle_src,
                                                            angle_dst, out, n_pairs);
    }
}

// Round 5
// 330.892 us; speedup vs baseline: 3.9583x; 1.2259x over previous
//
#include <hip/hip_runtime.h>
#include <math.h>

#define OUTC 304
#define BINW 128         // atoms per bin (= per accum block)
#define MAXB 400         // max bins supported by LDS staging
#define CAP  6144        // payload slots per bin (lambda ~5115 at 2M items)
#define SC_K 20          // LDS staging depth per bucket
#define SC_F 12          // flush every SC_F iterations (lambda ~7.9 per bucket)
#define OVF_CAP 65536

// ---------------- ecfp copy ----------------
__global__ __launch_bounds__(256) void k_ecfp(const float* __restrict__ ecfp,
                                              float* __restrict__ out, int total4) {
    int i = blockIdx.x * 256 + threadIdx.x;
    if (i >= total4) return;
    int row = i >> 2, c4 = i & 3;
    ((float4*)out)[row * (OUTC / 4) + c4] = ((const float4*)ecfp)[i];
}

__global__ __launch_bounds__(256) void k_zero(int* __restrict__ a, int n) {
    int i = blockIdx.x * 256 + threadIdx.x;
    if (i < n) a[i] = 0;
}

// ---------------- angular edge records: d12b | sw14b | sp2b ----------------
__global__ __launch_bounds__(256) void k_prep_edge(const float* __restrict__ angd,
                                                   const float* __restrict__ angsw,
                                                   const int* __restrict__ aedst,
                                                   const int* __restrict__ species,
                                                   unsigned* __restrict__ erec, int n) {
    int i = blockIdx.x * 256 + threadIdx.x;
    if (i >= n) return;
    int z = species[aedst[i]];
    unsigned sp = (z == 6) ? 1u : (z == 7) ? 2u : (z == 8) ? 3u : 0u;
    float d = angd[i], s = angsw[i];
    unsigned dq = (unsigned)fminf(fmaxf((d - 0.8f) * (4095.0f / 2.7f) + 0.5f, 0.f), 4095.f);
    unsigned sq = (unsigned)fminf(fmaxf(s * 16383.0f + 0.5f, 0.f), 16383.f);
    erec[i] = dq | (sq << 12) | (sp << 26);
}

// ============ LDS-staged counting scatter (radial) ============
// payload: x = dq16|sq16 ; y = loc7 | sp2<<7 | bb1<<9
__global__ __launch_bounds__(256) void k_scatter_rad(
        const float* __restrict__ dist, const float* __restrict__ sw,
        const int* __restrict__ bond_order, const int* __restrict__ esrc,
        const int* __restrict__ edst, const int* __restrict__ species,
        int* __restrict__ gcnt, uint2* __restrict__ payload,
        uint4* __restrict__ ovf, int* __restrict__ ovfc,
        int n, int span, int nb) {
    __shared__ uint2 stg[MAXB * SC_K];
    __shared__ int lcnt[MAXB];
    __shared__ int lbase[MAXB];
    __shared__ int pre[512];
    __shared__ int wsum[4];
    const int tid = threadIdx.x;
    for (int i = tid; i < nb; i += 256) lcnt[i] = 0;
    __syncthreads();
    int base = blockIdx.x * span;
    int end = min(base + span, n);
    if (base >= end) return;
    int pend = 0;
    for (int i0 = base; i0 < end; i0 += 256) {
        int e = i0 + tid;
        if (e < end) {
            float d = dist[e];
            float s = sw[e];
            int bo = bond_order[e];
            unsigned bb = (bo == 3 || bo == 5) ? 1u : 0u;
            int z = species[edst[e]];
            unsigned sp = (z == 6) ? 1u : (z == 7) ? 2u : (z == 8) ? 3u : 0u;
            int c = esrc[e];
            unsigned dq = (unsigned)fminf(fmaxf((d - 0.8f) * (65535.0f / 4.4f) + 0.5f, 0.f), 65535.f);
            unsigned sq = (unsigned)fminf(fmaxf(s * 65535.0f + 0.5f, 0.f), 65535.f);
            uint2 pl;
            pl.x = dq | (sq << 16);
            pl.y = (unsigned)(c & (BINW - 1)) | (sp << 7) | (bb << 9);
            int b = c >> 7;
            int slot = atomicAdd(&lcnt[b], 1);
            if (slot < SC_K) stg[b * SC_K + slot] = pl;
            else { int oi = atomicAdd(ovfc, 1); if (oi < OVF_CAP) ovf[oi] = make_uint4(pl.x, pl.y, (unsigned)c, 0u); }
        }
        bool last = (i0 + 256 >= end);
        if (++pend == SC_F || last) {
            pend = 0;
            __syncthreads();
            int lane = tid & 63, wid = tid >> 6;
            int b0 = 2 * tid, b1 = 2 * tid + 1;
            int ca = (b0 < nb) ? min(lcnt[b0], SC_K) : 0;
            int cb = (b1 < nb) ? min(lcnt[b1], SC_K) : 0;
            int s2 = ca + cb;
            int inc = s2;
#pragma unroll
            for (int dd = 1; dd < 64; dd <<= 1) {
                int u = __shfl_up(inc, dd);
                if (lane >= dd) inc += u;
            }
            if (lane == 63) wsum[wid] = inc;
            __syncthreads();
            int wbase = 0;
#pragma unroll
            for (int w = 0; w < 4; ++w) if (w < wid) wbase += wsum[w];
            int excl = wbase + inc - s2;
            pre[b0] = excl;
            pre[b1] = excl + ca;
            if (b0 < nb && ca > 0) lbase[b0] = atomicAdd(&gcnt[b0], ca);
            if (b1 < nb && cb > 0) lbase[b1] = atomicAdd(&gcnt[b1], cb);
            __syncthreads();
            int T = pre[nb];
            for (int t2 = tid; t2 < T; t2 += 256) {
                int lo = 0, hi = nb;
                while (hi - lo > 1) { int mid = (lo + hi) >> 1; if (pre[mid] <= t2) lo = mid; else hi = mid; }
                int b = lo, k = t2 - pre[b];
                uint2 pl = stg[b * SC_K + k];
                int gpos = lbase[b] + k;
                if (gpos < CAP) payload[(size_t)b * CAP + gpos] = pl;
                else { int oi = atomicAdd(ovfc, 1); if (oi < OVF_CAP) ovf[oi] = make_uint4(pl.x, pl.y, (unsigned)(b * BINW + (pl.y & (BINW - 1))), 0u); }
            }
            __syncthreads();
            for (int i = tid; i < nb; i += 256) lcnt[i] = 0;
            __syncthreads();
        }
    }
}

// ============ LDS-staged counting scatter (angular) ============
// payload: x = tq16|dq16 ; y = sq16 | loc7<<16 | pair4<<23
__global__ __launch_bounds__(256) void k_scatter_ang(
        const float* __restrict__ angles, const unsigned* __restrict__ erec,
        const int* __restrict__ central, const int* __restrict__ psrc,
        const int* __restrict__ pdst,
        int* __restrict__ gcnt, uint2* __restrict__ payload,
        uint4* __restrict__ ovf, int* __restrict__ ovfc,
        int n, int span, int nb) {
    __shared__ uint2 stg[MAXB * SC_K];
    __shared__ int lcnt[MAXB];
    __shared__ int lbase[MAXB];
    __shared__ int pre[512];
    __shared__ int wsum[4];
    const int tid = threadIdx.x;
    for (int i = tid; i < nb; i += 256) lcnt[i] = 0;
    __syncthreads();
    int base = blockIdx.x * span;
    int end = min(base + span, n);
    if (base >= end) return;
    int pend = 0;
    for (int i0 = base; i0 < end; i0 += 256) {
        int p = i0 + tid;
        if (p < end) {
            unsigned rs = erec[psrc[p]];
            unsigned rt = erec[pdst[p]];
            float dsrc = 0.8f + (float)(rs & 0xfffu) * (2.7f / 4095.0f);
            float dtgt = 0.8f + (float)(rt & 0xfffu) * (2.7f / 4095.0f);
            float ss = (float)((rs >> 12) & 0x3fffu) * (1.0f / 16383.0f);
            float st = (float)((rt >> 12) & 0x3fffu) * (1.0f / 16383.0f);
            int sps = (int)(rs >> 26), spt = (int)(rt >> 26);
            int i = min(sps, spt), j = max(sps, spt);
            unsigned pair = (unsigned)(i * 4 - (i * (i - 1)) / 2 + (j - i));
            float d12 = 0.5f * (dsrc + dtgt);
            float scale = 2.0f * ss * st;
            float th = angles[p];
            int c = central[p];
            unsigned tq = (unsigned)fminf(fmaxf(th * (65535.0f / 3.14159265358979f) + 0.5f, 0.f), 65535.f);
            unsigned dq = (unsigned)fminf(fmaxf((d12 - 0.8f) * (65535.0f / 2.7f) + 0.5f, 0.f), 65535.f);
            unsigned sq = (unsigned)fminf(fmaxf(scale * (65535.0f / 2.0f) + 0.5f, 0.f), 65535.f);
            uint2 pl;
            pl.x = tq | (dq << 16);
            pl.y = sq | ((unsigned)(c & (BINW - 1)) << 16) | (pair << 23);
            int b = c >> 7;
            int slot = atomicAdd(&lcnt[b], 1);
            if (slot < SC_K) stg[b * SC_K + slot] = pl;
            else { int oi = atomicAdd(ovfc, 1); if (oi < OVF_CAP) ovf[oi] = make_uint4(pl.x, pl.y, (unsigned)c, 1u); }
        }
        bool last = (i0 + 256 >= end);
        if (++pend == SC_F || last) {
            pend = 0;
            __syncthreads();
            int lane = tid & 63, wid = tid >> 6;
            int b0 = 2 * tid, b1 = 2 * tid + 1;
            int ca = (b0 < nb) ? min(lcnt[b0], SC_K) : 0;
            int cb = (b1 < nb) ? min(lcnt[b1], SC_K) : 0;
            int s2 = ca + cb;
            int inc = s2;
#pragma unroll
            for (int dd = 1; dd < 64; dd <<= 1) {
                int u = __shfl_up(inc, dd);
                if (lane >= dd) inc += u;
            }
            if (lane == 63) wsum[wid] = inc;
            __syncthreads();
            int wbase = 0;
#pragma unroll
            for (int w = 0; w < 4; ++w) if (w < wid) wbase += wsum[w];
            int excl = wbase + inc - s2;
            pre[b0] = excl;
            pre[b1] = excl + ca;
            if (b0 < nb && ca > 0) lbase[b0] = atomicAdd(&gcnt[b0], ca);
            if (b1 < nb && cb > 0) lbase[b1] = atomicAdd(&gcnt[b1], cb);
            __syncthreads();
            int T = pre[nb];
            for (int t2 = tid; t2 < T; t2 += 256) {
                int lo = 0, hi = nb;
                while (hi - lo > 1) { int mid = (lo + hi) >> 1; if (pre[mid] <= t2) lo = mid; else hi = mid; }
                int b = lo, k = t2 - pre[b];
                uint2 pl = stg[b * SC_K + k];
                int gpos = lbase[b] + k;
                if (gpos < CAP) payload[(size_t)b * CAP + gpos] = pl;
                else { int oi = atomicAdd(ovfc, 1); if (oi < OVF_CAP) ovf[oi] = make_uint4(pl.x, pl.y, (unsigned)(b * BINW + ((pl.y >> 16) & (BINW - 1))), 1u); }
            }
            __syncthreads();
            for (int i = tid; i < nb; i += 256) lcnt[i] = 0;
            __syncthreads();
        }
    }
}

// ---------------- radial accumulate: 128 atoms per block ----------------
__global__ __launch_bounds__(512) void k_accum_rad(const uint2* __restrict__ payload,
                                                   const int* __restrict__ gcnt,
                                                   float* __restrict__ out, int n_atoms) {
    __shared__ float acc[BINW * 128];   // 64 KB
    int b = blockIdx.x;
    for (int i = threadIdx.x; i < BINW * 128; i += 512) acc[i] = 0.f;
    __syncthreads();
    int len = min(gcnt[b], CAP);
    const uint2* pp = payload + (size_t)b * CAP;
    for (int r = threadIdx.x; r < len; r += 512) {
        uint2 pl = pp[r];
        float d = 0.8f + (float)(pl.x & 0xffffu) * (4.4f / 65535.0f);
        float coef = 0.25f * (float)(pl.x >> 16) * (1.0f / 65535.0f);
        int bidx = (int)(pl.y & 127u) * 128 + (int)((pl.y >> 7) & 3u) * 32 + (int)((pl.y >> 9) & 1u);
#pragma unroll
        for (int k = 0; k < 16; ++k) {
            float delta = d - (0.8f + 0.275f * (float)k);
            float v = coef * __expf(-16.0f * delta * delta);
            if (v > 1e-6f) atomicAdd(&acc[bidx + k * 2], v);
        }
    }
    __syncthreads();
    int a0 = b * BINW;
    for (int i = threadIdx.x; i < BINW * 128; i += 512) {
        int la = i >> 7, cc = i & 127;
        int atom = a0 + la;
        if (atom < n_atoms) out[(size_t)atom * OUTC + 16 + cc] = acc[i];
    }
}

// ---------------- angular accumulate: 128 atoms per block ----------------
__global__ __launch_bounds__(512) void k_accum_ang(const uint2* __restrict__ payload,
                                                   const int* __restrict__ gcnt,
                                                   float* __restrict__ out, int n_atoms) {
    __shared__ float acc[BINW * 160];   // 80 KB
    int b = blockIdx.x;
    for (int i = threadIdx.x; i < BINW * 160; i += 512) acc[i] = 0.f;
    __syncthreads();
    int len = min(gcnt[b], CAP);
    const uint2* pp = payload + (size_t)b * CAP;
    const float CZ[4] = {0.92387953251f, 0.38268343236f, -0.38268343236f, -0.92387953251f};
    const float SZ[4] = {0.38268343236f, 0.92387953251f, 0.92387953251f, 0.38268343236f};
    for (int r = threadIdx.x; r < len; r += 512) {
        uint2 pl = pp[r];
        float th    = (float)(pl.x & 0xffffu) * (3.14159265358979f / 65535.0f);
        float d12   = 0.8f + (float)(pl.x >> 16) * (2.7f / 65535.0f);
        float scale = (float)(pl.y & 0xffffu) * (2.0f / 65535.0f);
        int bidx = (int)((pl.y >> 16) & 127u) * 160 + (int)((pl.y >> 23) & 15u) * 16;
        float sth, cth;
        __sincosf(th, &sth, &cth);
        float f1[4];
#pragma unroll
        for (int zz = 0; zz < 4; ++zz) {
            float x = 0.5f + 0.5f * (cth * CZ[zz] + sth * SZ[zz]);
            float x2 = x * x, x4 = x2 * x2, x8 = x4 * x4, x16 = x8 * x8;
            f1[zz] = x16 * x16;
        }
#pragma unroll
        for (int a = 0; a < 4; ++a) {
            float da = d12 - (0.8f + 0.675f * (float)a);
            float f2 = __expf(-8.0f * da * da) * scale;
#pragma unroll
            for (int zz = 0; zz < 4; ++zz) {
                float v = f2 * f1[zz];
                if (v > 1e-6f) atomicAdd(&acc[bidx + a * 4 + zz], v);
            }
        }
    }
    __syncthreads();
    int a0 = b * BINW;
    for (int i = threadIdx.x; i < BINW * 160; i += 512) {
        int la = i / 160, cc = i - la * 160;
        int atom = a0 + la;
        if (atom < n_atoms) out[(size_t)atom * OUTC + 144 + cc] = acc[i];
    }
}

// ---------------- overflow spill (rare) ----------------
__global__ __launch_bounds__(256) void k_spill(const uint4* __restrict__ ovf,
                                               const int* __restrict__ ovfc,
                                               float* __restrict__ out) {
    int n = min(*ovfc, OVF_CAP);
    const float CZ[4] = {0.92387953251f, 0.38268343236f, -0.38268343236f, -0.92387953251f};
    const float SZ[4] = {0.38268343236f, 0.92387953251f, 0.92387953251f, 0.38268343236f};
    for (int idx = blockIdx.x * 256 + threadIdx.x; idx < n; idx += gridDim.x * 256) {
        uint4 e = ovf[idx];
        if (e.w == 0u) {   // radial
            float d = 0.8f + (float)(e.x & 0xffffu) * (4.4f / 65535.0f);
            float coef = 0.25f * (float)(e.x >> 16) * (1.0f / 65535.0f);
            int sp = (int)((e.y >> 7) & 3u), bb = (int)((e.y >> 9) & 1u);
            float* base = out + (size_t)e.z * OUTC + 16 + sp * 32 + bb;
            for (int k = 0; k < 16; ++k) {
                float delta = d - (0.8f + 0.275f * (float)k);
                float v = coef * __expf(-16.0f * delta * delta);
                if (v > 1e-6f) unsafeAtomicAdd(base + k * 2, v);
            }
        } else {           // angular
            float th    = (float)(e.x & 0xffffu) * (3.14159265358979f / 65535.0f);
            float d12   = 0.8f + (float)(e.x >> 16) * (2.7f / 65535.0f);
            float scale = (float)(e.y & 0xffffu) * (2.0f / 65535.0f);
            int pair = (int)((e.y >> 23) & 15u);
            float* base = out + (size_t)e.z * OUTC + 144 + pair * 16;
            float sth, cth;
            __sincosf(th, &sth, &cth);
            for (int zz = 0; zz < 4; ++zz) {
                float x = 0.5f + 0.5f * (cth * CZ[zz] + sth * SZ[zz]);
                float x2 = x * x, x4 = x2 * x2, x8 = x4 * x4, x16 = x8 * x8;
                float f1 = x16 * x16;
                for (int a = 0; a < 4; ++a) {
                    float da = d12 - (0.8f + 0.675f * (float)a);
                    float v = __expf(-8.0f * da * da) * scale * f1;
                    if (v > 1e-6f) unsafeAtomicAdd(base + a * 4 + zz, v);
                }
            }
        }
    }
}

// ================= fallback (round-1 atomic path) =================
__global__ __launch_bounds__(256) void k_init_fb(const float* __restrict__ ecfp,
                                                 float* __restrict__ out, int total4) {
    int i = blockIdx.x * 256 + threadIdx.x;
    if (i >= total4) return;
    int row = i / 76, c4 = i - row * 76;
    float4 v = make_float4(0.f, 0.f, 0.f, 0.f);
    if (c4 < 4) v = ((const float4*)ecfp)[row * 4 + c4];
    ((float4*)out)[i] = v;
}

__global__ __launch_bounds__(256) void k_radial_fb(const float* __restrict__ dist,
                                                   const float* __restrict__ sw,
                                                   const int* __restrict__ bond_order,
                                                   const int* __restrict__ esrc,
                                                   const int* __restrict__ edst,
                                                   const int* __restrict__ species,
                                                   float* __restrict__ out, int e_rad) {
    int e = blockIdx.x * 256 + threadIdx.x;
    if (e >= e_rad) return;
    float d = dist[e], s = sw[e];
    int bo = bond_order[e];
    int bb = (bo == 3 || bo == 5) ? 1 : 0;
    int z = species[edst[e]];
    int sp = (z == 6) ? 1 : (z == 7) ? 2 : (z == 8) ? 3 : 0;
    float* base = out + (size_t)esrc[e] * OUTC + 16 + sp * 32 + bb;
    float coef = 0.25f * s;
#pragma unroll
    for (int r = 0; r < 16; ++r) {
        float delta = d - (0.8f + 0.275f * (float)r);
        float v = coef * __expf(-16.0f * delta * delta);
        if (v > 6e-7f) unsafeAtomicAdd(base + r * 2, v);
    }
}

__global__ __launch_bounds__(256) void k_ang_fb(const float* __restrict__ angles,
                                                const float* __restrict__ angd,
                                                const float* __restrict__ angsw,
                                                const int* __restrict__ aedst,
                                                const int* __restrict__ species,
                                                const int* __restrict__ central,
                                                const int* __restrict__ psrc,
                                                const int* __restrict__ pdst,
                                                float* __restrict__ out, int n_pairs) {
    int p = blockIdx.x * 256 + threadIdx.x;
    if (p >= n_pairs) return;
    int is = psrc[p], it = pdst[p];
    float th = angles[p];
    float d12 = 0.5f * (angd[is] + angd[it]);
    float scale = 2.0f * angsw[is] * angsw[it];
    int zs = species[aedst[is]], zt = species[aedst[it]];
    int sps = (zs == 6) ? 1 : (zs == 7) ? 2 : (zs == 8) ? 3 : 0;
    int spt = (zt == 6) ? 1 : (zt == 7) ? 2 : (zt == 8) ? 3 : 0;
    int i = min(sps, spt), j = max(sps, spt);
    int pair = i * 4 - (i * (i - 1)) / 2 + (j - i);
    float sth, cth;
    __sincosf(th, &sth, &cth);
    const float CZ[4] = {0.92387953251f, 0.38268343236f, -0.38268343236f, -0.92387953251f};
    const float SZ[4] = {0.38268343236f, 0.92387953251f, 0.92387953251f, 0.38268343236f};
    float f1[4];
#pragma unroll
    for (int zz = 0; zz < 4; ++zz) {
        float x = 0.5f + 0.5f * (cth * CZ[zz] + sth * SZ[zz]);
        float x2 = x * x, x4 = x2 * x2, x8 = x4 * x4, x16 = x8 * x8;
        f1[zz] = x16 * x16;
    }
    float* base = out + (size_t)central[p] * OUTC + 144 + pair * 16;
#pragma unroll
    for (int a = 0; a < 4; ++a) {
        float da = d12 - (0.8f + 0.675f * (float)a);
        float f2 = __expf(-8.0f * da * da) * scale;
#pragma unroll
        for (int zz = 0; zz < 4; ++zz) {
            float v = f2 * f1[zz];
            if (v > 6e-7f) unsafeAtomicAdd(base + a * 4 + zz, v);
        }
    }
}

extern "C" void kernel_launch(void* const* d_in, const int* in_sizes, int n_in,
                              void* d_out, int out_size, void* d_ws, size_t ws_size,
                              hipStream_t stream) {
    const float* ecfp      = (const float*)d_in[0];
    const float* distances = (const float*)d_in[1];
    const float* sw        = (const float*)d_in[2];
    const float* angles    = (const float*)d_in[3];
    const float* angd      = (const float*)d_in[4];
    const float* angsw     = (const float*)d_in[5];
    const int*   species   = (const int*)d_in[6];
    const int*   bond_ord  = (const int*)d_in[7];
    const int*   edge_src  = (const int*)d_in[8];
    const int*   edge_dst  = (const int*)d_in[9];
    const int*   aedst     = (const int*)d_in[10];
    const int*   central   = (const int*)d_in[11];
    const int*   angle_src = (const int*)d_in[12];
    const int*   angle_dst = (const int*)d_in[13];
    float* out = (float*)d_out;

    const int e_rad   = in_sizes[1];
    const int n_pairs = in_sizes[3];
    const int e_ang   = in_sizes[4];
    const int n_atoms = in_sizes[6];

    const int NB = (n_atoms + BINW - 1) / BINW;

    size_t pay_bytes  = (size_t)NB * CAP * 8;
    size_t erec_bytes = ((size_t)e_ang * 4 + 15) & ~(size_t)15;
    size_t ovf_bytes  = (size_t)OVF_CAP * 16;
    size_t need = pay_bytes + erec_bytes + ovf_bytes + (size_t)(2 * NB + 1) * 4;

    bool cap_ok = (NB <= MAXB) &&
                  (e_rad  <= NB * (CAP - 512)) &&
                  (n_pairs <= NB * (CAP - 512));

    if (ws_size >= need && cap_ok) {
        uint2*    payload = (uint2*)d_ws;
        unsigned* erec    = (unsigned*)((char*)d_ws + pay_bytes);
        uint4*    ovf     = (uint4*)((char*)d_ws + pay_bytes + erec_bytes);
        int*      gcntR   = (int*)((char*)ovf + ovf_bytes);
        int*      gcntA   = gcntR + NB;
        int*      ovfc    = gcntA + NB;

        // scatter grid: ~512 blocks, span multiple of 256
        auto spanFor = [](int n) {
            int iters = (n + 255) / 256;
            int per = (iters + 511) / 512;
            return per * 256;
        };
        int spanR = spanFor(e_rad);
        int gridR = (e_rad + spanR - 1) / spanR;
        int spanA = spanFor(n_pairs);
        int gridA = (n_pairs + spanA - 1) / spanA;

        k_ecfp<<<(n_atoms * 4 + 255) / 256, 256, 0, stream>>>(ecfp, out, n_atoms * 4);
        k_zero<<<(2 * NB + 1 + 255) / 256, 256, 0, stream>>>(gcntR, 2 * NB + 1);
        k_prep_edge<<<(e_ang + 255) / 256, 256, 0, stream>>>(angd, angsw, aedst,
                                                             species, erec, e_ang);
        k_scatter_rad<<<gridR, 256, 0, stream>>>(distances, sw, bond_ord, edge_src,
                                                 edge_dst, species, gcntR, payload,
                                                 ovf, ovfc, e_rad, spanR, NB);
        k_accum_rad<<<NB, 512, 0, stream>>>(payload, gcntR, out, n_atoms);
        k_scatter_ang<<<gridA, 256, 0, stream>>>(angles, erec, central, angle_src,
                                                 angle_dst, gcntA, payload,
                                                 ovf, ovfc, n_pairs, spanA, NB);
        k_accum_ang<<<NB, 512, 0, stream>>>(payload, gcntA, out, n_atoms);
        k_spill<<<16, 256, 0, stream>>>(ovf, ovfc, out);
    } else {
        int total4 = n_atoms * (OUTC / 4);
        k_init_fb<<<(total4 + 255) / 256, 256, 0, stream>>>(ecfp, out, total4);
        k_radial_fb<<<(e_rad + 255) / 256, 256, 0, stream>>>(distances, sw, bond_ord,
                                                             edge_src, edge_dst, species,
                                                             out, e_rad);
        k_ang_fb<<<(n_pairs + 255) / 256, 256, 0, stream>>>(angles, angd, angsw, aedst,
                                                            species, central, angle_src,
                                                            angle_dst, out, n_pairs);
    }
}

// Round 6
// 323.551 us; speedup vs baseline: 4.0481x; 1.0227x over previous
//
#include <hip/hip_runtime.h>
#include <math.h>

#define OUTC 304
#define BINW 128         // atoms per scatter bin
#define MAXB 400         // max bins supported by LDS staging
#define CAP  6144        // payload slots per bin (lambda ~5115 at 2M items)
#define SC_K 20          // LDS staging depth per bucket
#define SC_F 12          // flush every SC_F iterations
#define OVF_CAP 65536

// ---------------- ecfp copy ----------------
__global__ __launch_bounds__(256) void k_ecfp(const float* __restrict__ ecfp,
                                              float* __restrict__ out, int total4) {
    int i = blockIdx.x * 256 + threadIdx.x;
    if (i >= total4) return;
    int row = i >> 2, c4 = i & 3;
    ((float4*)out)[row * (OUTC / 4) + c4] = ((const float4*)ecfp)[i];
}

__global__ __launch_bounds__(256) void k_zero(int* __restrict__ a, int n) {
    int i = blockIdx.x * 256 + threadIdx.x;
    if (i < n) a[i] = 0;
}

// ---------------- angular edge records: d12b | sw14b | sp2b ----------------
__global__ __launch_bounds__(256) void k_prep_edge(const float* __restrict__ angd,
                                                   const float* __restrict__ angsw,
                                                   const int* __restrict__ aedst,
                                                   const int* __restrict__ species,
                                                   unsigned* __restrict__ erec, int n) {
    int i = blockIdx.x * 256 + threadIdx.x;
    if (i >= n) return;
    int z = species[aedst[i]];
    unsigned sp = (z == 6) ? 1u : (z == 7) ? 2u : (z == 8) ? 3u : 0u;
    float d = angd[i], s = angsw[i];
    unsigned dq = (unsigned)fminf(fmaxf((d - 0.8f) * (4095.0f / 2.7f) + 0.5f, 0.f), 4095.f);
    unsigned sq = (unsigned)fminf(fmaxf(s * 16383.0f + 0.5f, 0.f), 16383.f);
    erec[i] = dq | (sq << 12) | (sp << 26);
}

// ============ LDS-staged counting scatter (radial) ============
// payload: x = dq16|sq16 ; y = loc7 | sp2<<7 | bb1<<9
__global__ __launch_bounds__(256) void k_scatter_rad(
        const float* __restrict__ dist, const float* __restrict__ sw,
        const int* __restrict__ bond_order, const int* __restrict__ esrc,
        const int* __restrict__ edst, const int* __restrict__ species,
        int* __restrict__ gcnt, uint2* __restrict__ payload,
        uint4* __restrict__ ovf, int* __restrict__ ovfc,
        int n, int span, int nb) {
    __shared__ uint2 stg[MAXB * SC_K];
    __shared__ int lcnt[MAXB];
    __shared__ int lbase[MAXB];
    __shared__ int pre[512];
    __shared__ int wsum[4];
    const int tid = threadIdx.x;
    for (int i = tid; i < nb; i += 256) lcnt[i] = 0;
    __syncthreads();
    int base = blockIdx.x * span;
    int end = min(base + span, n);
    if (base >= end) return;
    int pend = 0;
    for (int i0 = base; i0 < end; i0 += 256) {
        int e = i0 + tid;
        if (e < end) {
            float d = dist[e];
            float s = sw[e];
            int bo = bond_order[e];
            unsigned bb = (bo == 3 || bo == 5) ? 1u : 0u;
            int z = species[edst[e]];
            unsigned sp = (z == 6) ? 1u : (z == 7) ? 2u : (z == 8) ? 3u : 0u;
            int c = esrc[e];
            unsigned dq = (unsigned)fminf(fmaxf((d - 0.8f) * (65535.0f / 4.4f) + 0.5f, 0.f), 65535.f);
            unsigned sq = (unsigned)fminf(fmaxf(s * 65535.0f + 0.5f, 0.f), 65535.f);
            uint2 pl;
            pl.x = dq | (sq << 16);
            pl.y = (unsigned)(c & (BINW - 1)) | (sp << 7) | (bb << 9);
            int b = c >> 7;
            int slot = atomicAdd(&lcnt[b], 1);
            if (slot < SC_K) stg[b * SC_K + slot] = pl;
            else { int oi = atomicAdd(ovfc, 1); if (oi < OVF_CAP) ovf[oi] = make_uint4(pl.x, pl.y, (unsigned)c, 0u); }
        }
        bool last = (i0 + 256 >= end);
        if (++pend == SC_F || last) {
            pend = 0;
            __syncthreads();
            int lane = tid & 63, wid = tid >> 6;
            int b0 = 2 * tid, b1 = 2 * tid + 1;
            int ca = (b0 < nb) ? min(lcnt[b0], SC_K) : 0;
            int cb = (b1 < nb) ? min(lcnt[b1], SC_K) : 0;
            int s2 = ca + cb;
            int inc = s2;
#pragma unroll
            for (int dd = 1; dd < 64; dd <<= 1) {
                int u = __shfl_up(inc, dd);
                if (lane >= dd) inc += u;
            }
            if (lane == 63) wsum[wid] = inc;
            __syncthreads();
            int wbase = 0;
#pragma unroll
            for (int w = 0; w < 4; ++w) if (w < wid) wbase += wsum[w];
            int excl = wbase + inc - s2;
            pre[b0] = excl;
            pre[b1] = excl + ca;
            if (b0 < nb && ca > 0) lbase[b0] = atomicAdd(&gcnt[b0], ca);
            if (b1 < nb && cb > 0) lbase[b1] = atomicAdd(&gcnt[b1], cb);
            __syncthreads();
            int T = pre[nb];
            for (int t2 = tid; t2 < T; t2 += 256) {
                int lo = 0, hi = nb;
                while (hi - lo > 1) { int mid = (lo + hi) >> 1; if (pre[mid] <= t2) lo = mid; else hi = mid; }
                int b = lo, k = t2 - pre[b];
                uint2 pl = stg[b * SC_K + k];
                int gpos = lbase[b] + k;
                if (gpos < CAP) payload[(size_t)b * CAP + gpos] = pl;
                else { int oi = atomicAdd(ovfc, 1); if (oi < OVF_CAP) ovf[oi] = make_uint4(pl.x, pl.y, (unsigned)(b * BINW + (pl.y & (BINW - 1))), 0u); }
            }
            __syncthreads();
            for (int i = tid; i < nb; i += 256) lcnt[i] = 0;
            __syncthreads();
        }
    }
}

// ============ LDS-staged counting scatter (angular) ============
// payload: x = tq16|dq16 ; y = sq16 | loc7<<16 | pair4<<23
__global__ __launch_bounds__(256) void k_scatter_ang(
        const float* __restrict__ angles, const unsigned* __restrict__ erec,
        const int* __restrict__ central, const int* __restrict__ psrc,
        const int* __restrict__ pdst,
        int* __restrict__ gcnt, uint2* __restrict__ payload,
        uint4* __restrict__ ovf, int* __restrict__ ovfc,
        int n, int span, int nb) {
    __shared__ uint2 stg[MAXB * SC_K];
    __shared__ int lcnt[MAXB];
    __shared__ int lbase[MAXB];
    __shared__ int pre[512];
    __shared__ int wsum[4];
    const int tid = threadIdx.x;
    for (int i = tid; i < nb; i += 256) lcnt[i] = 0;
    __syncthreads();
    int base = blockIdx.x * span;
    int end = min(base + span, n);
    if (base >= end) return;
    int pend = 0;
    for (int i0 = base; i0 < end; i0 += 256) {
        int p = i0 + tid;
        if (p < end) {
            unsigned rs = erec[psrc[p]];
            unsigned rt = erec[pdst[p]];
            float dsrc = 0.8f + (float)(rs & 0xfffu) * (2.7f / 4095.0f);
            float dtgt = 0.8f + (float)(rt & 0xfffu) * (2.7f / 4095.0f);
            float ss = (float)((rs >> 12) & 0x3fffu) * (1.0f / 16383.0f);
            float st = (float)((rt >> 12) & 0x3fffu) * (1.0f / 16383.0f);
            int sps = (int)(rs >> 26), spt = (int)(rt >> 26);
            int i = min(sps, spt), j = max(sps, spt);
            unsigned pair = (unsigned)(i * 4 - (i * (i - 1)) / 2 + (j - i));
            float d12 = 0.5f * (dsrc + dtgt);
            float scale = 2.0f * ss * st;
            float th = angles[p];
            int c = central[p];
            unsigned tq = (unsigned)fminf(fmaxf(th * (65535.0f / 3.14159265358979f) + 0.5f, 0.f), 65535.f);
            unsigned dq = (unsigned)fminf(fmaxf((d12 - 0.8f) * (65535.0f / 2.7f) + 0.5f, 0.f), 65535.f);
            unsigned sq = (unsigned)fminf(fmaxf(scale * (65535.0f / 2.0f) + 0.5f, 0.f), 65535.f);
            uint2 pl;
            pl.x = tq | (dq << 16);
            pl.y = sq | ((unsigned)(c & (BINW - 1)) << 16) | (pair << 23);
            int b = c >> 7;
            int slot = atomicAdd(&lcnt[b], 1);
            if (slot < SC_K) stg[b * SC_K + slot] = pl;
            else { int oi = atomicAdd(ovfc, 1); if (oi < OVF_CAP) ovf[oi] = make_uint4(pl.x, pl.y, (unsigned)c, 1u); }
        }
        bool last = (i0 + 256 >= end);
        if (++pend == SC_F || last) {
            pend = 0;
            __syncthreads();
            int lane = tid & 63, wid = tid >> 6;
            int b0 = 2 * tid, b1 = 2 * tid + 1;
            int ca = (b0 < nb) ? min(lcnt[b0], SC_K) : 0;
            int cb = (b1 < nb) ? min(lcnt[b1], SC_K) : 0;
            int s2 = ca + cb;
            int inc = s2;
#pragma unroll
            for (int dd = 1; dd < 64; dd <<= 1) {
                int u = __shfl_up(inc, dd);
                if (lane >= dd) inc += u;
            }
            if (lane == 63) wsum[wid] = inc;
            __syncthreads();
            int wbase = 0;
#pragma unroll
            for (int w = 0; w < 4; ++w) if (w < wid) wbase += wsum[w];
            int excl = wbase + inc - s2;
            pre[b0] = excl;
            pre[b1] = excl + ca;
            if (b0 < nb && ca > 0) lbase[b0] = atomicAdd(&gcnt[b0], ca);
            if (b1 < nb && cb > 0) lbase[b1] = atomicAdd(&gcnt[b1], cb);
            __syncthreads();
            int T = pre[nb];
            for (int t2 = tid; t2 < T; t2 += 256) {
                int lo = 0, hi = nb;
                while (hi - lo > 1) { int mid = (lo + hi) >> 1; if (pre[mid] <= t2) lo = mid; else hi = mid; }
                int b = lo, k = t2 - pre[b];
                uint2 pl = stg[b * SC_K + k];
                int gpos = lbase[b] + k;
                if (gpos < CAP) payload[(size_t)b * CAP + gpos] = pl;
                else { int oi = atomicAdd(ovfc, 1); if (oi < OVF_CAP) ovf[oi] = make_uint4(pl.x, pl.y, (unsigned)(b * BINW + ((pl.y >> 16) & (BINW - 1))), 1u); }
            }
            __syncthreads();
            for (int i = tid; i < nb; i += 256) lcnt[i] = 0;
            __syncthreads();
        }
    }
}

// ---------------- radial accumulate: half-bin (64 atoms), padded LDS ----------------
__global__ __launch_bounds__(512) void k_accum_rad(const uint2* __restrict__ payload,
                                                   const int* __restrict__ gcnt,
                                                   float* __restrict__ out, int n_atoms) {
    __shared__ float acc[64 * 129];   // 33 KB, stride 129 breaks bank aliasing
    int b = blockIdx.x >> 1;
    int half = blockIdx.x & 1;
    for (int i = threadIdx.x; i < 64 * 129; i += 512) acc[i] = 0.f;
    __syncthreads();
    int len = min(gcnt[b], CAP);
    const uint2* pp = payload + (size_t)b * CAP;
    for (int r = threadIdx.x; r < len; r += 512) {
        uint2 pl = pp[r];
        if ((int)((pl.y >> 6) & 1u) != half) continue;
        float d = 0.8f + (float)(pl.x & 0xffffu) * (4.4f / 65535.0f);
        float coef = 0.25f * (float)(pl.x >> 16) * (1.0f / 65535.0f);
        int bidx = (int)(pl.y & 63u) * 129 + (int)((pl.y >> 7) & 3u) * 32 + (int)((pl.y >> 9) & 1u);
#pragma unroll
        for (int k = 0; k < 16; ++k) {
            float delta = d - (0.8f + 0.275f * (float)k);
            float v = coef * __expf(-16.0f * delta * delta);
            if (v > 1e-6f) atomicAdd(&acc[bidx + k * 2], v);
        }
    }
    __syncthreads();
    int a0 = b * BINW + half * 64;
    for (int i = threadIdx.x; i < 64 * 128; i += 512) {
        int la = i >> 7, cc = i & 127;
        int atom = a0 + la;
        if (atom < n_atoms) out[(size_t)atom * OUTC + 16 + cc] = acc[la * 129 + cc];
    }
}

// ---------------- angular accumulate: half-bin (64 atoms), padded LDS ----------------
__global__ __launch_bounds__(512) void k_accum_ang(const uint2* __restrict__ payload,
                                                   const int* __restrict__ gcnt,
                                                   float* __restrict__ out, int n_atoms) {
    __shared__ float acc[64 * 161];   // 41.2 KB, stride 161 breaks bank aliasing
    int b = blockIdx.x >> 1;
    int half = blockIdx.x & 1;
    for (int i = threadIdx.x; i < 64 * 161; i += 512) acc[i] = 0.f;
    __syncthreads();
    int len = min(gcnt[b], CAP);
    const uint2* pp = payload + (size_t)b * CAP;
    const float CZ[4] = {0.92387953251f, 0.38268343236f, -0.38268343236f, -0.92387953251f};
    const float SZ[4] = {0.38268343236f, 0.92387953251f, 0.92387953251f, 0.38268343236f};
    for (int r = threadIdx.x; r < len; r += 512) {
        uint2 pl = pp[r];
        if ((int)((pl.y >> 22) & 1u) != half) continue;
        float th    = (float)(pl.x & 0xffffu) * (3.14159265358979f / 65535.0f);
        float d12   = 0.8f + (float)(pl.x >> 16) * (2.7f / 65535.0f);
        float scale = (float)(pl.y & 0xffffu) * (2.0f / 65535.0f);
        int bidx = (int)((pl.y >> 16) & 63u) * 161 + (int)((pl.y >> 23) & 15u) * 16;
        float sth, cth;
        __sincosf(th, &sth, &cth);
        float f1[4];
#pragma unroll
        for (int zz = 0; zz < 4; ++zz) {
            float x = 0.5f + 0.5f * (cth * CZ[zz] + sth * SZ[zz]);
            float x2 = x * x, x4 = x2 * x2, x8 = x4 * x4, x16 = x8 * x8;
            f1[zz] = x16 * x16;
        }
#pragma unroll
        for (int a = 0; a < 4; ++a) {
            float da = d12 - (0.8f + 0.675f * (float)a);
            float f2 = __expf(-8.0f * da * da) * scale;
#pragma unroll
            for (int zz = 0; zz < 4; ++zz) {
                float v = f2 * f1[zz];
                if (v > 1e-6f) atomicAdd(&acc[bidx + a * 4 + zz], v);
            }
        }
    }
    __syncthreads();
    int a0 = b * BINW + half * 64;
    for (int i = threadIdx.x; i < 64 * 160; i += 512) {
        int la = i / 160, cc = i - la * 160;
        int atom = a0 + la;
        if (atom < n_atoms) out[(size_t)atom * OUTC + 144 + cc] = acc[la * 161 + cc];
    }
}

// ---------------- overflow spill (rare) ----------------
__global__ __launch_bounds__(256) void k_spill(const uint4* __restrict__ ovf,
                                               const int* __restrict__ ovfc,
                                               float* __restrict__ out) {
    int n = min(*ovfc, OVF_CAP);
    const float CZ[4] = {0.92387953251f, 0.38268343236f, -0.38268343236f, -0.92387953251f};
    const float SZ[4] = {0.38268343236f, 0.92387953251f, 0.92387953251f, 0.38268343236f};
    for (int idx = blockIdx.x * 256 + threadIdx.x; idx < n; idx += gridDim.x * 256) {
        uint4 e = ovf[idx];
        if (e.w == 0u) {   // radial
            float d = 0.8f + (float)(e.x & 0xffffu) * (4.4f / 65535.0f);
            float coef = 0.25f * (float)(e.x >> 16) * (1.0f / 65535.0f);
            int sp = (int)((e.y >> 7) & 3u), bb = (int)((e.y >> 9) & 1u);
            float* base = out + (size_t)e.z * OUTC + 16 + sp * 32 + bb;
            for (int k = 0; k < 16; ++k) {
                float delta = d - (0.8f + 0.275f * (float)k);
                float v = coef * __expf(-16.0f * delta * delta);
                if (v > 1e-6f) unsafeAtomicAdd(base + k * 2, v);
            }
        } else {           // angular
            float th    = (float)(e.x & 0xffffu) * (3.14159265358979f / 65535.0f);
            float d12   = 0.8f + (float)(e.x >> 16) * (2.7f / 65535.0f);
            float scale = (float)(e.y & 0xffffu) * (2.0f / 65535.0f);
            int pair = (int)((e.y >> 23) & 15u);
            float* base = out + (size_t)e.z * OUTC + 144 + pair * 16;
            float sth, cth;
            __sincosf(th, &sth, &cth);
            for (int zz = 0; zz < 4; ++zz) {
                float x = 0.5f + 0.5f * (cth * CZ[zz] + sth * SZ[zz]);
                float x2 = x * x, x4 = x2 * x2, x8 = x4 * x4, x16 = x8 * x8;
                float f1 = x16 * x16;
                for (int a = 0; a < 4; ++a) {
                    float da = d12 - (0.8f + 0.675f * (float)a);
                    float v = __expf(-8.0f * da * da) * scale * f1;
                    if (v > 1e-6f) unsafeAtomicAdd(base + a * 4 + zz, v);
                }
            }
        }
    }
}

// ================= fallback (round-1 atomic path) =================
__global__ __launch_bounds__(256) void k_init_fb(const float* __restrict__ ecfp,
                                                 float* __restrict__ out, int total4) {
    int i = blockIdx.x * 256 + threadIdx.x;
    if (i >= total4) return;
    int row = i / 76, c4 = i - row * 76;
    float4 v = make_float4(0.f, 0.f, 0.f, 0.f);
    if (c4 < 4) v = ((const float4*)ecfp)[row * 4 + c4];
    ((float4*)out)[i] = v;
}

__global__ __launch_bounds__(256) void k_radial_fb(const float* __restrict__ dist,
                                                   const float* __restrict__ sw,
                                                   const int* __restrict__ bond_order,
                                                   const int* __restrict__ esrc,
                                                   const int* __restrict__ edst,
                                                   const int* __restrict__ species,
                                                   float* __restrict__ out, int e_rad) {
    int e = blockIdx.x * 256 + threadIdx.x;
    if (e >= e_rad) return;
    float d = dist[e], s = sw[e];
    int bo = bond_order[e];
    int bb = (bo == 3 || bo == 5) ? 1 : 0;
    int z = species[edst[e]];
    int sp = (z == 6) ? 1 : (z == 7) ? 2 : (z == 8) ? 3 : 0;
    float* base = out + (size_t)esrc[e] * OUTC + 16 + sp * 32 + bb;
    float coef = 0.25f * s;
#pragma unroll
    for (int r = 0; r < 16; ++r) {
        float delta = d - (0.8f + 0.275f * (float)r);
        float v = coef * __expf(-16.0f * delta * delta);
        if (v > 6e-7f) unsafeAtomicAdd(base + r * 2, v);
    }
}

__global__ __launch_bounds__(256) void k_ang_fb(const float* __restrict__ angles,
                                                const float* __restrict__ angd,
                                                const float* __restrict__ angsw,
                                                const int* __restrict__ aedst,
                                                const int* __restrict__ species,
                                                const int* __restrict__ central,
                                                const int* __restrict__ psrc,
                                                const int* __restrict__ pdst,
                                                float* __restrict__ out, int n_pairs) {
    int p = blockIdx.x * 256 + threadIdx.x;
    if (p >= n_pairs) return;
    int is = psrc[p], it = pdst[p];
    float th = angles[p];
    float d12 = 0.5f * (angd[is] + angd[it]);
    float scale = 2.0f * angsw[is] * angsw[it];
    int zs = species[aedst[is]], zt = species[aedst[it]];
    int sps = (zs == 6) ? 1 : (zs == 7) ? 2 : (zs == 8) ? 3 : 0;
    int spt = (zt == 6) ? 1 : (zt == 7) ? 2 : (zt == 8) ? 3 : 0;
    int i = min(sps, spt), j = max(sps, spt);
    int pair = i * 4 - (i * (i - 1)) / 2 + (j - i);
    float sth, cth;
    __sincosf(th, &sth, &cth);
    const float CZ[4] = {0.92387953251f, 0.38268343236f, -0.38268343236f, -0.92387953251f};
    const float SZ[4] = {0.38268343236f, 0.92387953251f, 0.92387953251f, 0.38268343236f};
    float f1[4];
#pragma unroll
    for (int zz = 0; zz < 4; ++zz) {
        float x = 0.5f + 0.5f * (cth * CZ[zz] + sth * SZ[zz]);
        float x2 = x * x, x4 = x2 * x2, x8 = x4 * x4, x16 = x8 * x8;
        f1[zz] = x16 * x16;
    }
    float* base = out + (size_t)central[p] * OUTC + 144 + pair * 16;
#pragma unroll
    for (int a = 0; a < 4; ++a) {
        float da = d12 - (0.8f + 0.675f * (float)a);
        float f2 = __expf(-8.0f * da * da) * scale;
#pragma unroll
        for (int zz = 0; zz < 4; ++zz) {
            float v = f2 * f1[zz];
            if (v > 6e-7f) unsafeAtomicAdd(base + a * 4 + zz, v);
        }
    }
}

extern "C" void kernel_launch(void* const* d_in, const int* in_sizes, int n_in,
                              void* d_out, int out_size, void* d_ws, size_t ws_size,
                              hipStream_t stream) {
    const float* ecfp      = (const float*)d_in[0];
    const float* distances = (const float*)d_in[1];
    const float* sw        = (const float*)d_in[2];
    const float* angles    = (const float*)d_in[3];
    const float* angd      = (const float*)d_in[4];
    const float* angsw     = (const float*)d_in[5];
    const int*   species   = (const int*)d_in[6];
    const int*   bond_ord  = (const int*)d_in[7];
    const int*   edge_src  = (const int*)d_in[8];
    const int*   edge_dst  = (const int*)d_in[9];
    const int*   aedst     = (const int*)d_in[10];
    const int*   central   = (const int*)d_in[11];
    const int*   angle_src = (const int*)d_in[12];
    const int*   angle_dst = (const int*)d_in[13];
    float* out = (float*)d_out;

    const int e_rad   = in_sizes[1];
    const int n_pairs = in_sizes[3];
    const int e_ang   = in_sizes[4];
    const int n_atoms = in_sizes[6];

    const int NB = (n_atoms + BINW - 1) / BINW;

    size_t pay_bytes  = (size_t)NB * CAP * 8;
    size_t erec_bytes = ((size_t)e_ang * 4 + 15) & ~(size_t)15;
    size_t ovf_bytes  = (size_t)OVF_CAP * 16;
    size_t need = pay_bytes + erec_bytes + ovf_bytes + (size_t)(2 * NB + 1) * 4;

    bool cap_ok = (NB <= MAXB) &&
                  (e_rad  <= NB * (CAP - 512)) &&
                  (n_pairs <= NB * (CAP - 512));

    if (ws_size >= need && cap_ok) {
        uint2*    payload = (uint2*)d_ws;
        unsigned* erec    = (unsigned*)((char*)d_ws + pay_bytes);
        uint4*    ovf     = (uint4*)((char*)d_ws + pay_bytes + erec_bytes);
        int*      gcntR   = (int*)((char*)ovf + ovf_bytes);
        int*      gcntA   = gcntR + NB;
        int*      ovfc    = gcntA + NB;

        auto spanFor = [](int n) {
            int iters = (n + 255) / 256;
            int per = (iters + 511) / 512;
            return per * 256;
        };
        int spanR = spanFor(e_rad);
        int gridR = (e_rad + spanR - 1) / spanR;
        int spanA = spanFor(n_pairs);
        int gridA = (n_pairs + spanA - 1) / spanA;

        k_ecfp<<<(n_atoms * 4 + 255) / 256, 256, 0, stream>>>(ecfp, out, n_atoms * 4);
        k_zero<<<(2 * NB + 1 + 255) / 256, 256, 0, stream>>>(gcntR, 2 * NB + 1);
        k_prep_edge<<<(e_ang + 255) / 256, 256, 0, stream>>>(angd, angsw, aedst,
                                                             species, erec, e_ang);
        k_scatter_rad<<<gridR, 256, 0, stream>>>(distances, sw, bond_ord, edge_src,
                                                 edge_dst, species, gcntR, payload,
                                                 ovf, ovfc, e_rad, spanR, NB);
        k_accum_rad<<<2 * NB, 512, 0, stream>>>(payload, gcntR, out, n_atoms);
        k_scatter_ang<<<gridA, 256, 0, stream>>>(angles, erec, central, angle_src,
                                                 angle_dst, gcntA, payload,
                                                 ovf, ovfc, n_pairs, spanA, NB);
        k_accum_ang<<<2 * NB, 512, 0, stream>>>(payload, gcntA, out, n_atoms);
        k_spill<<<16, 256, 0, stream>>>(ovf, ovfc, out);
    } else {
        int total4 = n_atoms * (OUTC / 4);
        k_init_fb<<<(total4 + 255) / 256, 256, 0, stream>>>(ecfp, out, total4);
        k_radial_fb<<<(e_rad + 255) / 256, 256, 0, stream>>>(distances, sw, bond_ord,
                                                             edge_src, edge_dst, species,
                                                             out, e_rad);
        k_ang_fb<<<(n_pairs + 255) / 256, 256, 0, stream>>>(angles, angd, angsw, aedst,
                                                            species, central, angle_src,
                                                            angle_dst, out, n_pairs);
    }
}

// Round 7
// 302.005 us; speedup vs baseline: 4.3369x; 1.0713x over previous
//
#include <hip/hip_runtime.h>
#include <math.h>

#define OUTC 304
#define NBK  784         // max 64-atom bins (>= ceil(50000/64)=782)
#define CAP  3072        // payload slots per bin (lambda ~2558 at 2M items)
#define SC_K 12          // LDS staging depth per bucket
#define SC_F 8           // flush every SC_F iterations (lambda ~5.2/bucket)
#define OVF_CAP 65536

// ---------------- fused prep: zero counters + ecfp copy + angular edge records ----------------
__global__ __launch_bounds__(256) void k_prep(const float* __restrict__ angd,
                                              const float* __restrict__ angsw,
                                              const int* __restrict__ aedst,
                                              const int* __restrict__ species,
                                              unsigned* __restrict__ erec, int e_ang,
                                              const float* __restrict__ ecfp,
                                              float* __restrict__ out, int total4,
                                              int* __restrict__ gcnt, int nz) {
    int i = blockIdx.x * 256 + threadIdx.x;
    if (i < nz) gcnt[i] = 0;
    if (i < total4) {
        int row = i >> 2, c4 = i & 3;
        ((float4*)out)[row * (OUTC / 4) + c4] = ((const float4*)ecfp)[i];
    }
    if (i < e_ang) {
        int z = species[aedst[i]];
        unsigned sp = (z == 6) ? 1u : (z == 7) ? 2u : (z == 8) ? 3u : 0u;
        float d = angd[i], s = angsw[i];
        unsigned dq = (unsigned)fminf(fmaxf((d - 0.8f) * (4095.0f / 2.7f) + 0.5f, 0.f), 4095.f);
        unsigned sq = (unsigned)fminf(fmaxf(s * 16383.0f + 0.5f, 0.f), 16383.f);
        erec[i] = dq | (sq << 12) | (sp << 26);
    }
}

// ============ LDS-staged counting scatter (radial), 64-atom buckets ============
// payload: x = dq16|sq16 ; y = loc6 | sp2<<6 | bb1<<8
__global__ __launch_bounds__(512) void k_scatter_rad(
        const float* __restrict__ dist, const float* __restrict__ sw,
        const int* __restrict__ bond_order, const int* __restrict__ esrc,
        const int* __restrict__ edst, const int* __restrict__ species,
        int* __restrict__ gcnt, uint2* __restrict__ payload,
        uint4* __restrict__ ovf, int* __restrict__ ovfc,
        int n, int span, int nb) {
    __shared__ unsigned stgx[NBK * SC_K], stgy[NBK * SC_K];
    __shared__ int lcnt[NBK], lbase[NBK];
    __shared__ int pre[NBK + 2];
    __shared__ int wsum[8];
    const int tid = threadIdx.x;
    for (int i = tid; i < nb; i += 512) lcnt[i] = 0;
    __syncthreads();
    int base = blockIdx.x * span, end = min(base + span, n);
    if (base >= end) return;
    int pend = 0;
    for (int i0 = base; i0 < end; i0 += 512) {
        int e = i0 + tid;
        if (e < end) {
            float d = dist[e];
            float s = sw[e];
            int bo = bond_order[e];
            unsigned bb = (bo == 3 || bo == 5) ? 1u : 0u;
            int z = species[edst[e]];
            unsigned sp = (z == 6) ? 1u : (z == 7) ? 2u : (z == 8) ? 3u : 0u;
            int c = esrc[e];
            unsigned dq = (unsigned)fminf(fmaxf((d - 0.8f) * (65535.0f / 4.4f) + 0.5f, 0.f), 65535.f);
            unsigned sq = (unsigned)fminf(fmaxf(s * 65535.0f + 0.5f, 0.f), 65535.f);
            unsigned px = dq | (sq << 16);
            unsigned py = (unsigned)(c & 63) | (sp << 6) | (bb << 8);
            int b = c >> 6;
            int slot = atomicAdd(&lcnt[b], 1);
            if (slot < SC_K) { stgx[b * SC_K + slot] = px; stgy[b * SC_K + slot] = py; }
            else { int oi = atomicAdd(ovfc, 1); if (oi < OVF_CAP) ovf[oi] = make_uint4(px, py, (unsigned)c, 0u); }
        }
        if (++pend == SC_F || i0 + 512 >= end) {
            pend = 0;
            __syncthreads();
            int lane = tid & 63, wid = tid >> 6;
            int b0 = 2 * tid, b1 = 2 * tid + 1;
            int ca = (b0 < nb) ? min(lcnt[b0], SC_K) : 0;
            int cb = (b1 < nb) ? min(lcnt[b1], SC_K) : 0;
            int s2 = ca + cb, inc = s2;
#pragma unroll
            for (int dd = 1; dd < 64; dd <<= 1) {
                int u = __shfl_up(inc, dd);
                if (lane >= dd) inc += u;
            }
            if (lane == 63) wsum[wid] = inc;
            __syncthreads();
            int wbase = 0;
#pragma unroll
            for (int w = 0; w < 8; ++w) if (w < wid) wbase += wsum[w];
            int excl = wbase + inc - s2;
            if (b0 <= nb) pre[b0] = excl;
            if (b1 <= nb) pre[b1] = excl + ca;
            if (b0 < nb && ca > 0) lbase[b0] = atomicAdd(&gcnt[b0], ca);
            if (b1 < nb && cb > 0) lbase[b1] = atomicAdd(&gcnt[b1], cb);
            __syncthreads();
            int T = pre[nb];
            for (int t2 = tid; t2 < T; t2 += 512) {
                int lo = 0, hi = nb;
                while (hi - lo > 1) { int mid = (lo + hi) >> 1; if (pre[mid] <= t2) lo = mid; else hi = mid; }
                int b = lo, k = t2 - pre[b];
                unsigned px = stgx[b * SC_K + k], py = stgy[b * SC_K + k];
                int gpos = lbase[b] + k;
                if (gpos < CAP) payload[(size_t)b * CAP + gpos] = make_uint2(px, py);
                else { int oi = atomicAdd(ovfc, 1); if (oi < OVF_CAP) ovf[oi] = make_uint4(px, py, (unsigned)(b * 64 + (py & 63u)), 0u); }
            }
            __syncthreads();
            for (int i = tid; i < nb; i += 512) lcnt[i] = 0;
            __syncthreads();
        }
    }
}

// ============ LDS-staged counting scatter (angular), 64-atom buckets ============
// payload: x = tq16|dq16 ; y = sq16 | loc6<<16 | pair4<<22
__global__ __launch_bounds__(512) void k_scatter_ang(
        const float* __restrict__ angles, const unsigned* __restrict__ erec,
        const int* __restrict__ central, const int* __restrict__ psrc,
        const int* __restrict__ pdst,
        int* __restrict__ gcnt, uint2* __restrict__ payload,
        uint4* __restrict__ ovf, int* __restrict__ ovfc,
        int n, int span, int nb) {
    __shared__ unsigned stgx[NBK * SC_K], stgy[NBK * SC_K];
    __shared__ int lcnt[NBK], lbase[NBK];
    __shared__ int pre[NBK + 2];
    __shared__ int wsum[8];
    const int tid = threadIdx.x;
    for (int i = tid; i < nb; i += 512) lcnt[i] = 0;
    __syncthreads();
    int base = blockIdx.x * span, end = min(base + span, n);
    if (base >= end) return;
    int pend = 0;
    for (int i0 = base; i0 < end; i0 += 512) {
        int p = i0 + tid;
        if (p < end) {
            unsigned rs = erec[psrc[p]];
            unsigned rt = erec[pdst[p]];
            float dsrc = 0.8f + (float)(rs & 0xfffu) * (2.7f / 4095.0f);
            float dtgt = 0.8f + (float)(rt & 0xfffu) * (2.7f / 4095.0f);
            float ss = (float)((rs >> 12) & 0x3fffu) * (1.0f / 16383.0f);
            float st = (float)((rt >> 12) & 0x3fffu) * (1.0f / 16383.0f);
            int sps = (int)(rs >> 26), spt = (int)(rt >> 26);
            int i = min(sps, spt), j = max(sps, spt);
            unsigned pair = (unsigned)(i * 4 - (i * (i - 1)) / 2 + (j - i));
            float d12 = 0.5f * (dsrc + dtgt);
            float scale = 2.0f * ss * st;
            float th = angles[p];
            int c = central[p];
            unsigned tq = (unsigned)fminf(fmaxf(th * (65535.0f / 3.14159265358979f) + 0.5f, 0.f), 65535.f);
            unsigned dq = (unsigned)fminf(fmaxf((d12 - 0.8f) * (65535.0f / 2.7f) + 0.5f, 0.f), 65535.f);
            unsigned sq = (unsigned)fminf(fmaxf(scale * (65535.0f / 2.0f) + 0.5f, 0.f), 65535.f);
            unsigned px = tq | (dq << 16);
            unsigned py = sq | ((unsigned)(c & 63) << 16) | (pair << 22);
            int b = c >> 6;
            int slot = atomicAdd(&lcnt[b], 1);
            if (slot < SC_K) { stgx[b * SC_K + slot] = px; stgy[b * SC_K + slot] = py; }
            else { int oi = atomicAdd(ovfc, 1); if (oi < OVF_CAP) ovf[oi] = make_uint4(px, py, (unsigned)c, 1u); }
        }
        if (++pend == SC_F || i0 + 512 >= end) {
            pend = 0;
            __syncthreads();
            int lane = tid & 63, wid = tid >> 6;
            int b0 = 2 * tid, b1 = 2 * tid + 1;
            int ca = (b0 < nb) ? min(lcnt[b0], SC_K) : 0;
            int cb = (b1 < nb) ? min(lcnt[b1], SC_K) : 0;
            int s2 = ca + cb, inc = s2;
#pragma unroll
            for (int dd = 1; dd < 64; dd <<= 1) {
                int u = __shfl_up(inc, dd);
                if (lane >= dd) inc += u;
            }
            if (lane == 63) wsum[wid] = inc;
            __syncthreads();
            int wbase = 0;
#pragma unroll
            for (int w = 0; w < 8; ++w) if (w < wid) wbase += wsum[w];
            int excl = wbase + inc - s2;
            if (b0 <= nb) pre[b0] = excl;
            if (b1 <= nb) pre[b1] = excl + ca;
            if (b0 < nb && ca > 0) lbase[b0] = atomicAdd(&gcnt[b0], ca);
            if (b1 < nb && cb > 0) lbase[b1] = atomicAdd(&gcnt[b1], cb);
            __syncthreads();
            int T = pre[nb];
            for (int t2 = tid; t2 < T; t2 += 512) {
                int lo = 0, hi = nb;
                while (hi - lo > 1) { int mid = (lo + hi) >> 1; if (pre[mid] <= t2) lo = mid; else hi = mid; }
                int b = lo, k = t2 - pre[b];
                unsigned px = stgx[b * SC_K + k], py = stgy[b * SC_K + k];
                int gpos = lbase[b] + k;
                if (gpos < CAP) payload[(size_t)b * CAP + gpos] = make_uint2(px, py);
                else { int oi = atomicAdd(ovfc, 1); if (oi < OVF_CAP) ovf[oi] = make_uint4(px, py, (unsigned)(b * 64 + ((py >> 16) & 63u)), 1u); }
            }
            __syncthreads();
            for (int i = tid; i < nb; i += 512) lcnt[i] = 0;
            __syncthreads();
        }
    }
}

// ---------------- per-item accumulate helpers ----------------
__device__ __forceinline__ void proc_rad(uint2 pl, float* acc) {
    float d = 0.8f + (float)(pl.x & 0xffffu) * (4.4f / 65535.0f);
    float coef = 0.25f * (float)(pl.x >> 16) * (1.0f / 65535.0f);
    int bidx = (int)(pl.y & 63u) * 129 + (int)((pl.y >> 6) & 3u) * 32 + (int)((pl.y >> 8) & 1u);
#pragma unroll
    for (int k = 0; k < 16; ++k) {
        float delta = d - (0.8f + 0.275f * (float)k);
        float v = coef * __expf(-16.0f * delta * delta);
        if (v > 1e-6f) atomicAdd(&acc[bidx + k * 2], v);
    }
}

__device__ __forceinline__ void proc_ang(uint2 pl, float* acc) {
    const float CZ[4] = {0.92387953251f, 0.38268343236f, -0.38268343236f, -0.92387953251f};
    const float SZ[4] = {0.38268343236f, 0.92387953251f, 0.92387953251f, 0.38268343236f};
    float th    = (float)(pl.x & 0xffffu) * (3.14159265358979f / 65535.0f);
    float d12   = 0.8f + (float)(pl.x >> 16) * (2.7f / 65535.0f);
    float scale = (float)(pl.y & 0xffffu) * (2.0f / 65535.0f);
    int bidx = (int)((pl.y >> 16) & 63u) * 161 + (int)((pl.y >> 22) & 15u) * 16;
    float sth, cth;
    __sincosf(th, &sth, &cth);
    float f1[4];
#pragma unroll
    for (int zz = 0; zz < 4; ++zz) {
        float x = 0.5f + 0.5f * (cth * CZ[zz] + sth * SZ[zz]);
        float x2 = x * x, x4 = x2 * x2, x8 = x4 * x4, x16 = x8 * x8;
        f1[zz] = x16 * x16;
    }
#pragma unroll
    for (int a = 0; a < 4; ++a) {
        float da = d12 - (0.8f + 0.675f * (float)a);
        float f2 = __expf(-8.0f * da * da) * scale;
#pragma unroll
        for (int zz = 0; zz < 4; ++zz) {
            float v = f2 * f1[zz];
            if (v > 1e-6f) atomicAdd(&acc[bidx + a * 4 + zz], v);
        }
    }
}

// ---------------- radial accumulate: one 64-atom bin per block, 4-deep prefetch ----------------
__global__ __launch_bounds__(512) void k_accum_rad(const uint2* __restrict__ payload,
                                                   const int* __restrict__ gcnt,
                                                   float* __restrict__ out, int n_atoms) {
    __shared__ float acc[64 * 129];   // 33 KB, padded stride
    int b = blockIdx.x;
    for (int i = threadIdx.x; i < 64 * 129; i += 512) acc[i] = 0.f;
    __syncthreads();
    int len = min(gcnt[b], CAP);
    const uint2* pp = payload + (size_t)b * CAP;
    for (int r = threadIdx.x; r < len; r += 2048) {
        uint2 p0 = pp[r];
        bool h1 = r + 512 < len, h2 = r + 1024 < len, h3 = r + 1536 < len;
        uint2 p1, p2, p3;
        if (h1) p1 = pp[r + 512];
        if (h2) p2 = pp[r + 1024];
        if (h3) p3 = pp[r + 1536];
        proc_rad(p0, acc);
        if (h1) proc_rad(p1, acc);
        if (h2) proc_rad(p2, acc);
        if (h3) proc_rad(p3, acc);
    }
    __syncthreads();
    int a0 = b * 64;
    for (int i = threadIdx.x; i < 64 * 128; i += 512) {
        int la = i >> 7, cc = i & 127;
        int atom = a0 + la;
        if (atom < n_atoms) out[(size_t)atom * OUTC + 16 + cc] = acc[la * 129 + cc];
    }
}

// ---------------- angular accumulate: one 64-atom bin per block, 4-deep prefetch ----------------
__global__ __launch_bounds__(512) void k_accum_ang(const uint2* __restrict__ payload,
                                                   const int* __restrict__ gcnt,
                                                   float* __restrict__ out, int n_atoms) {
    __shared__ float acc[64 * 161];   // 41 KB, padded stride
    int b = blockIdx.x;
    for (int i = threadIdx.x; i < 64 * 161; i += 512) acc[i] = 0.f;
    __syncthreads();
    int len = min(gcnt[b], CAP);
    const uint2* pp = payload + (size_t)b * CAP;
    for (int r = threadIdx.x; r < len; r += 2048) {
        uint2 p0 = pp[r];
        bool h1 = r + 512 < len, h2 = r + 1024 < len, h3 = r + 1536 < len;
        uint2 p1, p2, p3;
        if (h1) p1 = pp[r + 512];
        if (h2) p2 = pp[r + 1024];
        if (h3) p3 = pp[r + 1536];
        proc_ang(p0, acc);
        if (h1) proc_ang(p1, acc);
        if (h2) proc_ang(p2, acc);
        if (h3) proc_ang(p3, acc);
    }
    __syncthreads();
    int a0 = b * 64;
    for (int i = threadIdx.x; i < 64 * 160; i += 512) {
        int la = i / 160, cc = i - la * 160;
        int atom = a0 + la;
        if (atom < n_atoms) out[(size_t)atom * OUTC + 144 + cc] = acc[la * 161 + cc];
    }
}

// ---------------- overflow spill (rare) ----------------
__global__ __launch_bounds__(256) void k_spill(const uint4* __restrict__ ovf,
                                               const int* __restrict__ ovfc,
                                               float* __restrict__ out) {
    int n = min(*ovfc, OVF_CAP);
    const float CZ[4] = {0.92387953251f, 0.38268343236f, -0.38268343236f, -0.92387953251f};
    const float SZ[4] = {0.38268343236f, 0.92387953251f, 0.92387953251f, 0.38268343236f};
    for (int idx = blockIdx.x * 256 + threadIdx.x; idx < n; idx += gridDim.x * 256) {
        uint4 e = ovf[idx];
        if (e.w == 0u) {   // radial
            float d = 0.8f + (float)(e.x & 0xffffu) * (4.4f / 65535.0f);
            float coef = 0.25f * (float)(e.x >> 16) * (1.0f / 65535.0f);
            int sp = (int)((e.y >> 6) & 3u), bb = (int)((e.y >> 8) & 1u);
            float* base = out + (size_t)e.z * OUTC + 16 + sp * 32 + bb;
            for (int k = 0; k < 16; ++k) {
                float delta = d - (0.8f + 0.275f * (float)k);
                float v = coef * __expf(-16.0f * delta * delta);
                if (v > 1e-6f) unsafeAtomicAdd(base + k * 2, v);
            }
        } else {           // angular
            float th    = (float)(e.x & 0xffffu) * (3.14159265358979f / 65535.0f);
            float d12   = 0.8f + (float)(e.x >> 16) * (2.7f / 65535.0f);
            float scale = (float)(e.y & 0xffffu) * (2.0f / 65535.0f);
            int pair = (int)((e.y >> 22) & 15u);
            float* base = out + (size_t)e.z * OUTC + 144 + pair * 16;
            float sth, cth;
            __sincosf(th, &sth, &cth);
            for (int zz = 0; zz < 4; ++zz) {
                float x = 0.5f + 0.5f * (cth * CZ[zz] + sth * SZ[zz]);
                float x2 = x * x, x4 = x2 * x2, x8 = x4 * x4, x16 = x8 * x8;
                float f1 = x16 * x16;
                for (int a = 0; a < 4; ++a) {
                    float da = d12 - (0.8f + 0.675f * (float)a);
                    float v = __expf(-8.0f * da * da) * scale * f1;
                    if (v > 1e-6f) unsafeAtomicAdd(base + a * 4 + zz, v);
                }
            }
        }
    }
}

// ================= fallback (round-1 atomic path) =================
__global__ __launch_bounds__(256) void k_init_fb(const float* __restrict__ ecfp,
                                                 float* __restrict__ out, int total4) {
    int i = blockIdx.x * 256 + threadIdx.x;
    if (i >= total4) return;
    int row = i / 76, c4 = i - row * 76;
    float4 v = make_float4(0.f, 0.f, 0.f, 0.f);
    if (c4 < 4) v = ((const float4*)ecfp)[row * 4 + c4];
    ((float4*)out)[i] = v;
}

__global__ __launch_bounds__(256) void k_radial_fb(const float* __restrict__ dist,
                                                   const float* __restrict__ sw,
                                                   const int* __restrict__ bond_order,
                                                   const int* __restrict__ esrc,
                                                   const int* __restrict__ edst,
                                                   const int* __restrict__ species,
                                                   float* __restrict__ out, int e_rad) {
    int e = blockIdx.x * 256 + threadIdx.x;
    if (e >= e_rad) return;
    float d = dist[e], s = sw[e];
    int bo = bond_order[e];
    int bb = (bo == 3 || bo == 5) ? 1 : 0;
    int z = species[edst[e]];
    int sp = (z == 6) ? 1 : (z == 7) ? 2 : (z == 8) ? 3 : 0;
    float* base = out + (size_t)esrc[e] * OUTC + 16 + sp * 32 + bb;
    float coef = 0.25f * s;
#pragma unroll
    for (int r = 0; r < 16; ++r) {
        float delta = d - (0.8f + 0.275f * (float)r);
        float v = coef * __expf(-16.0f * delta * delta);
        if (v > 6e-7f) unsafeAtomicAdd(base + r * 2, v);
    }
}

__global__ __launch_bounds__(256) void k_ang_fb(const float* __restrict__ angles,
                                                const float* __restrict__ angd,
                                                const float* __restrict__ angsw,
                                                const int* __restrict__ aedst,
                                                const int* __restrict__ species,
                                                const int* __restrict__ central,
                                                const int* __restrict__ psrc,
                                                const int* __restrict__ pdst,
                                                float* __restrict__ out, int n_pairs) {
    int p = blockIdx.x * 256 + threadIdx.x;
    if (p >= n_pairs) return;
    int is = psrc[p], it = pdst[p];
    float th = angles[p];
    float d12 = 0.5f * (angd[is] + angd[it]);
    float scale = 2.0f * angsw[is] * angsw[it];
    int zs = species[aedst[is]], zt = species[aedst[it]];
    int sps = (zs == 6) ? 1 : (zs == 7) ? 2 : (zs == 8) ? 3 : 0;
    int spt = (zt == 6) ? 1 : (zt == 7) ? 2 : (zt == 8) ? 3 : 0;
    int i = min(sps, spt), j = max(sps, spt);
    int pair = i * 4 - (i * (i - 1)) / 2 + (j - i);
    float sth, cth;
    __sincosf(th, &sth, &cth);
    const float CZ[4] = {0.92387953251f, 0.38268343236f, -0.38268343236f, -0.92387953251f};
    const float SZ[4] = {0.38268343236f, 0.92387953251f, 0.92387953251f, 0.38268343236f};
    float f1[4];
#pragma unroll
    for (int zz = 0; zz < 4; ++zz) {
        float x = 0.5f + 0.5f * (cth * CZ[zz] + sth * SZ[zz]);
        float x2 = x * x, x4 = x2 * x2, x8 = x4 * x4, x16 = x8 * x8;
        f1[zz] = x16 * x16;
    }
    float* base = out + (size_t)central[p] * OUTC + 144 + pair * 16;
#pragma unroll
    for (int a = 0; a < 4; ++a) {
        float da = d12 - (0.8f + 0.675f * (float)a);
        float f2 = __expf(-8.0f * da * da) * scale;
#pragma unroll
        for (int zz = 0; zz < 4; ++zz) {
            float v = f2 * f1[zz];
            if (v > 6e-7f) unsafeAtomicAdd(base + a * 4 + zz, v);
        }
    }
}

extern "C" void kernel_launch(void* const* d_in, const int* in_sizes, int n_in,
                              void* d_out, int out_size, void* d_ws, size_t ws_size,
                              hipStream_t stream) {
    const float* ecfp      = (const float*)d_in[0];
    const float* distances = (const float*)d_in[1];
    const float* sw        = (const float*)d_in[2];
    const float* angles    = (const float*)d_in[3];
    const float* angd      = (const float*)d_in[4];
    const float* angsw     = (const float*)d_in[5];
    const int*   species   = (const int*)d_in[6];
    const int*   bond_ord  = (const int*)d_in[7];
    const int*   edge_src  = (const int*)d_in[8];
    const int*   edge_dst  = (const int*)d_in[9];
    const int*   aedst     = (const int*)d_in[10];
    const int*   central   = (const int*)d_in[11];
    const int*   angle_src = (const int*)d_in[12];
    const int*   angle_dst = (const int*)d_in[13];
    float* out = (float*)d_out;

    const int e_rad   = in_sizes[1];
    const int n_pairs = in_sizes[3];
    const int e_ang   = in_sizes[4];
    const int n_atoms = in_sizes[6];

    const int NB = (n_atoms + 63) / 64;   // 64-atom bins

    size_t pay_bytes  = (size_t)NB * CAP * 8;
    size_t erec_bytes = ((size_t)e_ang * 4 + 15) & ~(size_t)15;
    size_t ovf_bytes  = (size_t)OVF_CAP * 16;
    size_t need = pay_bytes + erec_bytes + ovf_bytes + (size_t)(2 * NB + 1) * 4;

    bool cap_ok = (NB <= NBK) &&
                  (e_rad  <= (size_t)NB * (CAP - 256)) &&
                  (n_pairs <= (size_t)NB * (CAP - 256));

    if (ws_size >= need && cap_ok) {
        uint2*    payload = (uint2*)d_ws;
        unsigned* erec    = (unsigned*)((char*)d_ws + pay_bytes);
        uint4*    ovf     = (uint4*)((char*)d_ws + pay_bytes + erec_bytes);
        int*      gcntR   = (int*)((char*)ovf + ovf_bytes);
        int*      gcntA   = gcntR + NB;
        int*      ovfc    = gcntA + NB;

        const int span = SC_F * 2 * 512;   // 16 chunk-iterations per block
        int gridR = (e_rad + span - 1) / span;
        int gridA = (n_pairs + span - 1) / span;

        int total4 = n_atoms * 4;
        int nz = 2 * NB + 1;
        int prepN = max(e_ang, max(total4, nz));
        k_prep<<<(prepN + 255) / 256, 256, 0, stream>>>(angd, angsw, aedst, species,
                                                        erec, e_ang, ecfp, out, total4,
                                                        gcntR, nz);
        k_scatter_rad<<<gridR, 512, 0, stream>>>(distances, sw, bond_ord, edge_src,
                                                 edge_dst, species, gcntR, payload,
                                                 ovf, ovfc, e_rad, span, NB);
        k_accum_rad<<<NB, 512, 0, stream>>>(payload, gcntR, out, n_atoms);
        k_scatter_ang<<<gridA, 512, 0, stream>>>(angles, erec, central, angle_src,
                                                 angle_dst, gcntA, payload,
                                                 ovf, ovfc, n_pairs, span, NB);
        k_accum_ang<<<NB, 512, 0, stream>>>(payload, gcntA, out, n_atoms);
        k_spill<<<16, 256, 0, stream>>>(ovf, ovfc, out);
    } else {
        int total4 = n_atoms * (OUTC / 4);
        k_init_fb<<<(total4 + 255) / 256, 256, 0, stream>>>(ecfp, out, total4);
        k_radial_fb<<<(e_rad + 255) / 256, 256, 0, stream>>>(distances, sw, bond_ord,
                                                             edge_src, edge_dst, species,
                                                             out, e_rad);
        k_ang_fb<<<(n_pairs + 255) / 256, 256, 0, stream>>>(angles, angd, angsw, aedst,
                                                            species, central, angle_src,
                                                            angle_dst, out, n_pairs);
    }
}